// Round 1
// baseline (1530.522 us; speedup 1.0000x reference)
//
#include <hip/hip_runtime.h>
#include <cstdint>
#include <cstddef>

#define NREL 8

// ---------------------------------------------------------------------------
// deg[d*8+r] += 1 for every edge  (per-(dst,rel) in-degree, shared by layers)
// ---------------------------------------------------------------------------
__global__ __launch_bounds__(256) void deg_kernel(const int* __restrict__ dst,
                                                  const int* __restrict__ et,
                                                  float* __restrict__ deg, int E) {
  int e = blockIdx.x * 256 + threadIdx.x;
  if (e < E) unsafeAtomicAdd(&deg[(size_t)dst[e] * NREL + et[e]], 1.0f);
}

// ---------------------------------------------------------------------------
// shared 64x64 fp32 tile FMA (As: [row][k] padded, Bs: [k][col])
// ---------------------------------------------------------------------------
__device__ __forceinline__ void fma_tile(const float (*As)[68], const float (*Bs)[64],
                                         int tx, int ty, float acc[4][4]) {
#pragma unroll
  for (int k = 0; k < 64; ++k) {
    float4 b = *(const float4*)&Bs[k][tx * 4];
    float a0 = As[ty * 4 + 0][k];
    float a1 = As[ty * 4 + 1][k];
    float a2 = As[ty * 4 + 2][k];
    float a3 = As[ty * 4 + 3][k];
    acc[0][0] += a0 * b.x; acc[0][1] += a0 * b.y; acc[0][2] += a0 * b.z; acc[0][3] += a0 * b.w;
    acc[1][0] += a1 * b.x; acc[1][1] += a1 * b.y; acc[1][2] += a1 * b.z; acc[1][3] += a1 * b.w;
    acc[2][0] += a2 * b.x; acc[2][1] += a2 * b.y; acc[2][2] += a2 * b.z; acc[2][3] += a2 * b.w;
    acc[3][0] += a3 * b.x; acc[3][1] += a3 * b.y; acc[3][2] += a3 * b.z; acc[3][3] += a3 * b.w;
  }
}

// ---------------------------------------------------------------------------
// xt[n, rb*64+j] = sum_k x[n,k] * W1[r0+rb, k, j]   (K=128, per-relation N=64)
// ---------------------------------------------------------------------------
__global__ __launch_bounds__(256) void gemm1_kernel(const float* __restrict__ x,
                                                    const float* __restrict__ W1,
                                                    float* __restrict__ xt,
                                                    int M, int r0, int G) {
  __shared__ float As[64][68];
  __shared__ float Bs[64][64];
  const int tid = threadIdx.x;
  const int tx = tid & 15, ty = tid >> 4;
  const int row0 = blockIdx.x * 64;
  const int rb = blockIdx.y;
  const float* Wr = W1 + (size_t)(r0 + rb) * (128 * 64);
  float acc[4][4] = {};
  for (int k0 = 0; k0 < 128; k0 += 64) {
#pragma unroll
    for (int i = 0; i < 4; ++i) {
      int idx = tid + 256 * i;
      int row = idx >> 4, k4 = (idx & 15) * 4;
      float4 v = make_float4(0.f, 0.f, 0.f, 0.f);
      if (row0 + row < M)
        v = *(const float4*)&x[(size_t)(row0 + row) * 128 + k0 + k4];
      *(float4*)&As[row][k4] = v;
      *(float4*)&Bs[row][k4] = *(const float4*)&Wr[(size_t)(k0 + row) * 64 + k4];
    }
    __syncthreads();
    fma_tile(As, Bs, tx, ty, acc);
    __syncthreads();
  }
  const int stride = G * 64;
#pragma unroll
  for (int m = 0; m < 4; ++m) {
    int row = row0 + ty * 4 + m;
    if (row < M) {
      float4 o = make_float4(acc[m][0], acc[m][1], acc[m][2], acc[m][3]);
      *(float4*)&xt[(size_t)row * stride + rb * 64 + tx * 4] = o;
    }
  }
}

// ---------------------------------------------------------------------------
// hb[n,j] = relu(hb[n,j] + sum_k x[n,k]*root1[k,j] + b1[j])   (in place)
// ---------------------------------------------------------------------------
__global__ __launch_bounds__(256) void rootrelu_kernel(const float* __restrict__ x,
                                                       const float* __restrict__ root,
                                                       const float* __restrict__ b1,
                                                       float* __restrict__ hb, int M) {
  __shared__ float As[64][68];
  __shared__ float Bs[64][64];
  const int tid = threadIdx.x;
  const int tx = tid & 15, ty = tid >> 4;
  const int row0 = blockIdx.x * 64;
  float acc[4][4] = {};
  for (int k0 = 0; k0 < 128; k0 += 64) {
#pragma unroll
    for (int i = 0; i < 4; ++i) {
      int idx = tid + 256 * i;
      int row = idx >> 4, k4 = (idx & 15) * 4;
      float4 v = make_float4(0.f, 0.f, 0.f, 0.f);
      if (row0 + row < M)
        v = *(const float4*)&x[(size_t)(row0 + row) * 128 + k0 + k4];
      *(float4*)&As[row][k4] = v;
      *(float4*)&Bs[row][k4] = *(const float4*)&root[(size_t)(k0 + row) * 64 + k4];
    }
    __syncthreads();
    fma_tile(As, Bs, tx, ty, acc);
    __syncthreads();
  }
  float4 bb = *(const float4*)&b1[tx * 4];
#pragma unroll
  for (int m = 0; m < 4; ++m) {
    int row = row0 + ty * 4 + m;
    if (row < M) {
      float* hp = &hb[(size_t)row * 64 + tx * 4];
      float4 h = *(const float4*)hp;
      h.x = fmaxf(h.x + acc[m][0] + bb.x, 0.f);
      h.y = fmaxf(h.y + acc[m][1] + bb.y, 0.f);
      h.z = fmaxf(h.z + acc[m][2] + bb.z, 0.f);
      h.w = fmaxf(h.w + acc[m][3] + bb.w, 0.f);
      *(float4*)hp = h;
    }
  }
}

// ---------------------------------------------------------------------------
// layer-1 scatter: agg[dst, j] += xt[src, (et-r0)*64+j] / max(deg[dst,et],1)
// one wave per edge, lane = feature
// ---------------------------------------------------------------------------
__global__ __launch_bounds__(256) void scatter1_kernel(const int* __restrict__ src,
                                                       const int* __restrict__ dst,
                                                       const int* __restrict__ et,
                                                       const float* __restrict__ deg,
                                                       const float* __restrict__ xt,
                                                       float* __restrict__ agg,
                                                       int E, int r0, int G) {
  int e = (blockIdx.x * 256 + threadIdx.x) >> 6;
  if (e >= E) return;
  int r = et[e];
  int rb = r - r0;
  if (rb < 0 || rb >= G) return;
  int lane = threadIdx.x & 63;
  int s = src[e], d = dst[e];
  float nrm = 1.0f / fmaxf(deg[(size_t)d * NREL + r], 1.0f);
  float v = xt[(size_t)s * (G * 64) + rb * 64 + lane] * nrm;
  unsafeAtomicAdd(&agg[(size_t)d * 64 + lane], v);
}

// ---------------------------------------------------------------------------
// layer-2 scatter (aggregate-first): y2[dst, (et-r0)*64+j] += hb[src, j]
// ---------------------------------------------------------------------------
__global__ __launch_bounds__(256) void scatter2_kernel(const int* __restrict__ src,
                                                       const int* __restrict__ dst,
                                                       const int* __restrict__ et,
                                                       const float* __restrict__ hb,
                                                       float* __restrict__ y2,
                                                       int E, int r0, int G) {
  int e = (blockIdx.x * 256 + threadIdx.x) >> 6;
  if (e >= E) return;
  int r = et[e];
  int rb = r - r0;
  if (rb < 0 || rb >= G) return;
  int lane = threadIdx.x & 63;
  int s = src[e], d = dst[e];
  float v = hb[(size_t)s * 64 + lane];
  unsafeAtomicAdd(&y2[(size_t)d * (G * 64) + rb * 64 + lane], v);
}

// ---------------------------------------------------------------------------
// out[n, cb*64+j] += sum_rb sum_k (y2[n, rb*64+k]/max(deg[n,r0+rb],1)) * W2[r0+rb, k, cb*64+j]
// ---------------------------------------------------------------------------
__global__ __launch_bounds__(256) void gemm2_kernel(const float* __restrict__ y2,
                                                    const float* __restrict__ W2,
                                                    const float* __restrict__ deg,
                                                    float* __restrict__ out,
                                                    int M, int r0, int G) {
  __shared__ float As[64][68];
  __shared__ float Bs[64][64];
  const int tid = threadIdx.x;
  const int tx = tid & 15, ty = tid >> 4;
  const int row0 = blockIdx.x * 64;
  const int cb = blockIdx.y;  // column block of 64 within 128
  float acc[4][4] = {};
  for (int rb = 0; rb < G; ++rb) {
    int r = r0 + rb;
    const float* Wr = W2 + (size_t)r * (64 * 128);
#pragma unroll
    for (int i = 0; i < 4; ++i) {
      int idx = tid + 256 * i;
      int row = idx >> 4, k4 = (idx & 15) * 4;
      float4 v = make_float4(0.f, 0.f, 0.f, 0.f);
      if (row0 + row < M) {
        v = *(const float4*)&y2[(size_t)(row0 + row) * (G * 64) + rb * 64 + k4];
        float sc = 1.0f / fmaxf(deg[(size_t)(row0 + row) * NREL + r], 1.0f);
        v.x *= sc; v.y *= sc; v.z *= sc; v.w *= sc;
      }
      *(float4*)&As[row][k4] = v;
      *(float4*)&Bs[row][k4] = *(const float4*)&Wr[(size_t)row * 128 + cb * 64 + k4];
    }
    __syncthreads();
    fma_tile(As, Bs, tx, ty, acc);
    __syncthreads();
  }
#pragma unroll
  for (int m = 0; m < 4; ++m) {
    int row = row0 + ty * 4 + m;
    if (row < M) {
      float* op = &out[(size_t)row * 128 + cb * 64 + tx * 4];
      float4 o = *(const float4*)op;
      o.x += acc[m][0]; o.y += acc[m][1]; o.z += acc[m][2]; o.w += acc[m][3];
      *(float4*)op = o;
    }
  }
}

// ---------------------------------------------------------------------------
// out[n, cb*64+j] += sum_k hb[n,k]*root2[k, cb*64+j] + b2[cb*64+j]   (K=64)
// ---------------------------------------------------------------------------
__global__ __launch_bounds__(256) void final_kernel(const float* __restrict__ hb,
                                                    const float* __restrict__ root2,
                                                    const float* __restrict__ b2,
                                                    float* __restrict__ out, int M) {
  __shared__ float As[64][68];
  __shared__ float Bs[64][64];
  const int tid = threadIdx.x;
  const int tx = tid & 15, ty = tid >> 4;
  const int row0 = blockIdx.x * 64;
  const int cb = blockIdx.y;
  float acc[4][4] = {};
#pragma unroll
  for (int i = 0; i < 4; ++i) {
    int idx = tid + 256 * i;
    int row = idx >> 4, k4 = (idx & 15) * 4;
    float4 v = make_float4(0.f, 0.f, 0.f, 0.f);
    if (row0 + row < M)
      v = *(const float4*)&hb[(size_t)(row0 + row) * 64 + k4];
    *(float4*)&As[row][k4] = v;
    *(float4*)&Bs[row][k4] = *(const float4*)&root2[(size_t)row * 128 + cb * 64 + k4];
  }
  __syncthreads();
  fma_tile(As, Bs, tx, ty, acc);
  __syncthreads();
  float4 bb = *(const float4*)&b2[cb * 64 + tx * 4];
#pragma unroll
  for (int m = 0; m < 4; ++m) {
    int row = row0 + ty * 4 + m;
    if (row < M) {
      float* op = &out[(size_t)row * 128 + cb * 64 + tx * 4];
      float4 o = *(const float4*)op;
      o.x += acc[m][0] + bb.x; o.y += acc[m][1] + bb.y;
      o.z += acc[m][2] + bb.z; o.w += acc[m][3] + bb.w;
      *(float4*)op = o;
    }
  }
}

// ---------------------------------------------------------------------------
extern "C" void kernel_launch(void* const* d_in, const int* in_sizes, int n_in,
                              void* d_out, int out_size, void* d_ws, size_t ws_size,
                              hipStream_t stream) {
  const float* x     = (const float*)d_in[0];
  const int*   ei    = (const int*)d_in[1];
  const int*   et    = (const int*)d_in[2];
  const float* W1    = (const float*)d_in[3];
  const float* root1 = (const float*)d_in[4];
  const float* b1    = (const float*)d_in[5];
  const float* W2    = (const float*)d_in[6];
  const float* root2 = (const float*)d_in[7];
  const float* b2    = (const float*)d_in[8];
  float* out = (float*)d_out;

  const int M = in_sizes[0] / 128;   // 100000
  const int E = in_sizes[2];         // 1600000
  const int* srcp = ei;
  const int* dstp = ei + E;

  const size_t hb_b  = (size_t)M * 64 * sizeof(float);
  const size_t deg_b = (size_t)M * NREL * sizeof(float);
  int G = 8;
  while (G > 1 && hb_b + deg_b + (size_t)M * G * 64 * sizeof(float) > ws_size) G >>= 1;
  const size_t xt_b = (size_t)M * G * 64 * sizeof(float);

  char* p = (char*)d_ws;
  float* xt  = (float*)p; p += xt_b;   // layer1 xt / layer2 y2 (shared)
  float* hb  = (float*)p; p += hb_b;   // layer1 agg -> h (in place)
  float* deg = (float*)p;

  hipMemsetAsync(deg, 0, deg_b, stream);
  hipMemsetAsync(hb, 0, hb_b, stream);
  hipMemsetAsync(d_out, 0, (size_t)out_size * sizeof(float), stream);

  deg_kernel<<<(E + 255) / 256, 256, 0, stream>>>(dstp, et, deg, E);

  const int MB = (M + 63) / 64;
  const int SB = (E * 64 + 255) / 256;   // one wave per edge

  // ---- layer 1: transform-first ----
  for (int r0 = 0; r0 < NREL; r0 += G) {
    gemm1_kernel<<<dim3(MB, G), 256, 0, stream>>>(x, W1, xt, M, r0, G);
    scatter1_kernel<<<SB, 256, 0, stream>>>(srcp, dstp, et, deg, xt, hb, E, r0, G);
  }
  rootrelu_kernel<<<dim3(MB, 1), 256, 0, stream>>>(x, root1, b1, hb, M);

  // ---- layer 2: aggregate-first ----
  for (int r0 = 0; r0 < NREL; r0 += G) {
    hipMemsetAsync(xt, 0, xt_b, stream);
    scatter2_kernel<<<SB, 256, 0, stream>>>(srcp, dstp, et, hb, xt, E, r0, G);
    gemm2_kernel<<<dim3(MB, 2), 256, 0, stream>>>(xt, W2, deg, out, M, r0, G);
  }
  final_kernel<<<dim3(MB, 2), 256, 0, stream>>>(hb, root2, b2, out, M);
}

// Round 2
// 782.633 us; speedup vs baseline: 1.9556x; 1.9556x over previous
//
#include <hip/hip_runtime.h>
#include <cstdint>
#include <cstddef>

#define NREL 8

typedef __attribute__((ext_vector_type(8))) short bfrag8;   // 8 bf16 (4 VGPR)
typedef __attribute__((ext_vector_type(4))) float facc4;    // mfma accumulator

__device__ __forceinline__ ushort f2bf(float f) {           // fp32 -> bf16 RNE
  union { float f; uint u; } v; v.f = f;
  uint u = v.u + 0x7fffu + ((v.u >> 16) & 1u);
  return (ushort)(u >> 16);
}
__device__ __forceinline__ float bf2f(ushort u) {
  union { uint u; float f; } v; v.u = ((uint)u) << 16;
  return v.f;
}

// ---------------------------------------------------------------------------
// per-(dst,rel) in-degree
// ---------------------------------------------------------------------------
__global__ __launch_bounds__(256) void deg_kernel(const int* __restrict__ dst,
                                                  const int* __restrict__ et,
                                                  float* __restrict__ deg, int E) {
  int e = blockIdx.x * 256 + threadIdx.x;
  if (e < E) unsafeAtomicAdd(&deg[(size_t)dst[e] * NREL + et[e]], 1.0f);
}

// ---------------------------------------------------------------------------
// transpose-convert weights: out_bf16[r][n][k] = in_f32[r][k][n]
// ---------------------------------------------------------------------------
__global__ __launch_bounds__(256) void cvt_wt_kernel(const float* __restrict__ in,
                                                     ushort* __restrict__ out,
                                                     int R, int K, int N) {
  int idx = blockIdx.x * 256 + threadIdx.x;
  if (idx >= R * K * N) return;
  int r = idx / (K * N);
  int rem = idx - r * K * N;
  int n = rem / K;
  int k = rem - n * K;
  out[idx] = f2bf(in[(size_t)r * K * N + (size_t)k * N + n]);
}

// ---------------------------------------------------------------------------
// xt[m][r*64+n] = bf16( sum_k x[m][k] * W1[r][k][n] )   MFMA, swapped operands
// block: 64 rows x (8 rel x 64 cols); 4 waves, wave = 16 rows
// ---------------------------------------------------------------------------
__global__ __launch_bounds__(256) void gemm_xt_kernel(const float* __restrict__ x,
                                                      const ushort* __restrict__ W1t,
                                                      ushort* __restrict__ xt, int M) {
  __shared__ __align__(16) ushort Axs[64][136];   // x tile bf16, +8 pad
  __shared__ __align__(16) ushort Bws[64][136];   // Wt tile bf16
  const int tid = threadIdx.x;
  const int w = tid >> 6, l = tid & 63;
  const int rows0 = blockIdx.x * 64;
  // stage + convert x tile
#pragma unroll
  for (int i = 0; i < 8; ++i) {
    int g = tid + 256 * i;            // 2048 groups of 4 elems
    int row = g >> 5, c4 = (g & 31) * 4;
    int rr = rows0 + row; if (rr >= M) rr = M - 1;
    float4 v = *(const float4*)&x[(size_t)rr * 128 + c4];
    *(ushort4*)&Axs[row][c4] = make_ushort4(f2bf(v.x), f2bf(v.y), f2bf(v.z), f2bf(v.w));
  }
  __syncthreads();
  const int mrow = w * 16 + (l & 15);
  const int koff = (l >> 4) * 8;
  bfrag8 xf[4];
#pragma unroll
  for (int kc = 0; kc < 4; ++kc)
    xf[kc] = *(const bfrag8*)&Axs[mrow][kc * 32 + koff];
  const int m = rows0 + mrow;
  for (int r = 0; r < NREL; ++r) {
    __syncthreads();
#pragma unroll
    for (int i = 0; i < 8; ++i) {
      int g = tid + 256 * i;
      int row = g >> 5, c4 = (g & 31) * 4;
      *(ushort4*)&Bws[row][c4] = *(const ushort4*)&W1t[((size_t)r * 64 + row) * 128 + c4];
    }
    __syncthreads();
#pragma unroll
    for (int ct = 0; ct < 4; ++ct) {
      facc4 acc = {0.f, 0.f, 0.f, 0.f};
#pragma unroll
      for (int kc = 0; kc < 4; ++kc) {
        bfrag8 af = *(const bfrag8*)&Bws[ct * 16 + (l & 15)][kc * 32 + koff];
        acc = __builtin_amdgcn_mfma_f32_16x16x32_bf16(af, xf[kc], acc, 0, 0, 0);
      }
      if (m < M) {
        int n0 = ct * 16 + (l >> 4) * 4;   // lane holds 4 consecutive cols
        *(ushort4*)&xt[(size_t)m * 512 + r * 64 + n0] =
            make_ushort4(f2bf(acc[0]), f2bf(acc[1]), f2bf(acc[2]), f2bf(acc[3]));
      }
    }
  }
}

// ---------------------------------------------------------------------------
// packed-bf16 atomic scatter: to[dst*512 + r*64 + j] += from[src*fstride + r*frel + j]
// 32 threads per edge, 2 features per thread
// ---------------------------------------------------------------------------
__global__ __launch_bounds__(256) void scatter_kernel(const int* __restrict__ srcp,
                                                      const int* __restrict__ dstp,
                                                      const int* __restrict__ etp,
                                                      const ushort* __restrict__ from,
                                                      ushort* __restrict__ to,
                                                      int E, int fstride, int frel) {
  int t = blockIdx.x * 256 + threadIdx.x;
  int e = t >> 5;
  if (e >= E) return;
  int j2 = (t & 31) << 1;
  int s = srcp[e], d = dstp[e], r = etp[e];
  uint v = *(const uint*)&from[(size_t)s * fstride + r * frel + j2];
  if (v == 0u) return;   // both bf16 zero (common after relu) -> skip atomic
  ushort* tp = &to[(size_t)d * 512 + r * 64 + j2];
  asm volatile("global_atomic_pk_add_bf16 %0, %1, off"
               :: "v"((uint64_t)(uintptr_t)tp), "v"(v) : "memory");
}

// ---------------------------------------------------------------------------
// hb[m][n] = bf16( relu( sum_r y1[m][r][n]/max(deg[m][r],1) + (x root1)[m][n] + b1[n] ) )
// ---------------------------------------------------------------------------
__global__ __launch_bounds__(256) void reduce_h_kernel(const float* __restrict__ x,
                                                       const ushort* __restrict__ r1t,
                                                       const float* __restrict__ b1,
                                                       const ushort* __restrict__ y1,
                                                       const float* __restrict__ deg,
                                                       ushort* __restrict__ hb, int M) {
  __shared__ __align__(16) ushort Axs[64][136];
  __shared__ __align__(16) ushort Bws[64][136];
  const int tid = threadIdx.x;
  const int w = tid >> 6, l = tid & 63;
  const int rows0 = blockIdx.x * 64;
#pragma unroll
  for (int i = 0; i < 8; ++i) {
    int g = tid + 256 * i;
    int row = g >> 5, c4 = (g & 31) * 4;
    int rr = rows0 + row; if (rr >= M) rr = M - 1;
    float4 v = *(const float4*)&x[(size_t)rr * 128 + c4];
    *(ushort4*)&Axs[row][c4] = make_ushort4(f2bf(v.x), f2bf(v.y), f2bf(v.z), f2bf(v.w));
    *(ushort4*)&Bws[row][c4] = *(const ushort4*)&r1t[(size_t)row * 128 + c4];
  }
  __syncthreads();
  const int mrow = w * 16 + (l & 15);
  const int koff = (l >> 4) * 8;
  const int m = rows0 + mrow;
  const int mc = (m < M) ? m : (M - 1);
  bfrag8 xf[4];
#pragma unroll
  for (int kc = 0; kc < 4; ++kc)
    xf[kc] = *(const bfrag8*)&Axs[mrow][kc * 32 + koff];
  facc4 acc[4] = {};
#pragma unroll
  for (int ct = 0; ct < 4; ++ct)
#pragma unroll
    for (int kc = 0; kc < 4; ++kc) {
      bfrag8 af = *(const bfrag8*)&Bws[ct * 16 + (l & 15)][kc * 32 + koff];
      acc[ct] = __builtin_amdgcn_mfma_f32_16x16x32_bf16(af, xf[kc], acc[ct], 0, 0, 0);
    }
  float idg[NREL];
#pragma unroll
  for (int r = 0; r < NREL; ++r)
    idg[r] = 1.0f / fmaxf(deg[(size_t)mc * NREL + r], 1.0f);
#pragma unroll
  for (int ct = 0; ct < 4; ++ct) {
    int n0 = ct * 16 + (l >> 4) * 4;
    float s0 = 0.f, s1 = 0.f, s2 = 0.f, s3 = 0.f;
#pragma unroll
    for (int r = 0; r < NREL; ++r) {
      ushort4 u = *(const ushort4*)&y1[(size_t)mc * 512 + r * 64 + n0];
      s0 += bf2f(u.x) * idg[r];
      s1 += bf2f(u.y) * idg[r];
      s2 += bf2f(u.z) * idg[r];
      s3 += bf2f(u.w) * idg[r];
    }
    float4 bb = *(const float4*)&b1[n0];
    float h0 = fmaxf(acc[ct][0] + s0 + bb.x, 0.f);
    float h1 = fmaxf(acc[ct][1] + s1 + bb.y, 0.f);
    float h2 = fmaxf(acc[ct][2] + s2 + bb.z, 0.f);
    float h3 = fmaxf(acc[ct][3] + s3 + bb.w, 0.f);
    if (m < M)
      *(ushort4*)&hb[(size_t)m * 64 + n0] =
          make_ushort4(f2bf(h0), f2bf(h1), f2bf(h2), f2bf(h3));
  }
}

// ---------------------------------------------------------------------------
// out[m][n] = sum_r (y2[m][r][:]/max(deg,1)) W2[r][:][n] + (h root2)[m][n] + b2[n]
// ---------------------------------------------------------------------------
__global__ __launch_bounds__(256) void gemm_out_kernel(const ushort* __restrict__ hb,
                                                       const ushort* __restrict__ y2,
                                                       const ushort* __restrict__ W2t,
                                                       const ushort* __restrict__ r2t,
                                                       const float* __restrict__ b2,
                                                       const float* __restrict__ deg,
                                                       float* __restrict__ out, int M) {
  __shared__ __align__(16) ushort Bws[128][72];   // [n][k] bf16, +8 pad
  const int tid = threadIdx.x;
  const int w = tid >> 6, l = tid & 63;
  const int rows0 = blockIdx.x * 64;
  const int mrow = w * 16 + (l & 15);
  const int koff = (l >> 4) * 8;
  const int m = rows0 + mrow;
  const int mc = (m < M) ? m : (M - 1);
  facc4 oacc[8] = {};
  // ---- root2 part ----
#pragma unroll
  for (int i = 0; i < 8; ++i) {
    int g = tid + 256 * i;                 // 2048 groups of 4
    int row = g >> 4, c4 = (g & 15) * 4;
    *(ushort4*)&Bws[row][c4] = *(const ushort4*)&r2t[(size_t)row * 64 + c4];
  }
  __syncthreads();
  {
    bfrag8 h0 = *(const bfrag8*)&hb[(size_t)mc * 64 + koff];
    bfrag8 h1 = *(const bfrag8*)&hb[(size_t)mc * 64 + 32 + koff];
#pragma unroll
    for (int ct = 0; ct < 8; ++ct) {
      bfrag8 a0 = *(const bfrag8*)&Bws[ct * 16 + (l & 15)][koff];
      bfrag8 a1 = *(const bfrag8*)&Bws[ct * 16 + (l & 15)][32 + koff];
      oacc[ct] = __builtin_amdgcn_mfma_f32_16x16x32_bf16(a0, h0, oacc[ct], 0, 0, 0);
      oacc[ct] = __builtin_amdgcn_mfma_f32_16x16x32_bf16(a1, h1, oacc[ct], 0, 0, 0);
    }
  }
  // ---- relation parts, 1/deg folded after fresh accumulation ----
  for (int r = 0; r < NREL; ++r) {
    __syncthreads();
#pragma unroll
    for (int i = 0; i < 8; ++i) {
      int g = tid + 256 * i;
      int row = g >> 4, c4 = (g & 15) * 4;
      *(ushort4*)&Bws[row][c4] = *(const ushort4*)&W2t[((size_t)r * 128 + row) * 64 + c4];
    }
    __syncthreads();
    float sc = 1.0f / fmaxf(deg[(size_t)mc * NREL + r], 1.0f);
    bfrag8 y0 = *(const bfrag8*)&y2[(size_t)mc * 512 + r * 64 + koff];
    bfrag8 y1f = *(const bfrag8*)&y2[(size_t)mc * 512 + r * 64 + 32 + koff];
#pragma unroll
    for (int ct = 0; ct < 8; ++ct) {
      facc4 t = {0.f, 0.f, 0.f, 0.f};
      bfrag8 a0 = *(const bfrag8*)&Bws[ct * 16 + (l & 15)][koff];
      bfrag8 a1 = *(const bfrag8*)&Bws[ct * 16 + (l & 15)][32 + koff];
      t = __builtin_amdgcn_mfma_f32_16x16x32_bf16(a0, y0, t, 0, 0, 0);
      t = __builtin_amdgcn_mfma_f32_16x16x32_bf16(a1, y1f, t, 0, 0, 0);
      oacc[ct] += t * sc;
    }
  }
  if (m < M) {
#pragma unroll
    for (int ct = 0; ct < 8; ++ct) {
      int n0 = ct * 16 + (l >> 4) * 4;
      float4 bb = *(const float4*)&b2[n0];
      float4 o = make_float4(oacc[ct][0] + bb.x, oacc[ct][1] + bb.y,
                             oacc[ct][2] + bb.z, oacc[ct][3] + bb.w);
      *(float4*)&out[(size_t)m * 128 + n0] = o;
    }
  }
}

// ---------------------------------------------------------------------------
extern "C" void kernel_launch(void* const* d_in, const int* in_sizes, int n_in,
                              void* d_out, int out_size, void* d_ws, size_t ws_size,
                              hipStream_t stream) {
  const float* x     = (const float*)d_in[0];
  const int*   ei    = (const int*)d_in[1];
  const int*   et    = (const int*)d_in[2];
  const float* W1    = (const float*)d_in[3];
  const float* root1 = (const float*)d_in[4];
  const float* b1    = (const float*)d_in[5];
  const float* W2    = (const float*)d_in[6];
  const float* root2 = (const float*)d_in[7];
  const float* b2    = (const float*)d_in[8];
  float* out = (float*)d_out;

  const int M = in_sizes[0] / 128;   // 100000
  const int E = in_sizes[2];         // 1600000
  const int* srcp = ei;
  const int* dstp = ei + E;

  // workspace layout (~221 MB; round-1 run proved ws_size >= 233 MB)
  char* p = (char*)d_ws;
  ushort* xt  = (ushort*)p; p += (size_t)M * 512 * 2;   // layer1 xt / layer2 y2 (alias)
  ushort* y1  = (ushort*)p; p += (size_t)M * 512 * 2;   // per-(dst,rel) bf16 sums
  ushort* hb  = (ushort*)p; p += (size_t)M * 64 * 2;    // h (bf16)
  float*  deg = (float*)p;  p += (size_t)M * NREL * 4;
  ushort* W1t = (ushort*)p; p += (size_t)NREL * 64 * 128 * 2;
  ushort* r1t = (ushort*)p; p += (size_t)64 * 128 * 2;
  ushort* W2t = (ushort*)p; p += (size_t)NREL * 128 * 64 * 2;
  ushort* r2t = (ushort*)p; p += (size_t)128 * 64 * 2;
  ushort* y2 = xt;

  // weight transpose-converts (tiny)
  cvt_wt_kernel<<<(NREL * 128 * 64 + 255) / 256, 256, 0, stream>>>(W1, W1t, NREL, 128, 64);
  cvt_wt_kernel<<<(128 * 64 + 255) / 256, 256, 0, stream>>>(root1, r1t, 1, 128, 64);
  cvt_wt_kernel<<<(NREL * 64 * 128 + 255) / 256, 256, 0, stream>>>(W2, W2t, NREL, 64, 128);
  cvt_wt_kernel<<<(64 * 128 + 255) / 256, 256, 0, stream>>>(root2, r2t, 1, 64, 128);

  hipMemsetAsync(deg, 0, (size_t)M * NREL * 4, stream);
  deg_kernel<<<(E + 255) / 256, 256, 0, stream>>>(dstp, et, deg, E);

  const int MB64 = (M + 63) / 64;
  const int SB = (int)(((long long)E * 32 + 255) / 256);

  // ---- layer 1: transform -> per-(dst,rel) bf16 scatter -> fp32 reduce+root+relu
  hipMemsetAsync(y1, 0, (size_t)M * 512 * 2, stream);
  gemm_xt_kernel<<<MB64, 256, 0, stream>>>(x, W1t, xt, M);
  scatter_kernel<<<SB, 256, 0, stream>>>(srcp, dstp, et, xt, y1, E, 512, 64);
  reduce_h_kernel<<<MB64, 256, 0, stream>>>(x, r1t, b1, y1, deg, hb, M);

  // ---- layer 2: per-(dst,rel) bf16 scatter -> fused GEMM(+root2,+b2) ----
  hipMemsetAsync(y2, 0, (size_t)M * 512 * 2, stream);   // after scatter1 (stream order)
  scatter_kernel<<<SB, 256, 0, stream>>>(srcp, dstp, et, hb, y2, E, 64, 0);
  gemm_out_kernel<<<MB64, 256, 0, stream>>>(hb, y2, W2t, r2t, b2, deg, out, M);
}

// Round 3
// 542.616 us; speedup vs baseline: 2.8206x; 1.4423x over previous
//
#include <hip/hip_runtime.h>
#include <cstdint>
#include <cstddef>

#define NREL 8

typedef __attribute__((ext_vector_type(8))) short bfrag8;   // 8 bf16 (4 VGPR)
typedef __attribute__((ext_vector_type(4))) float facc4;    // mfma accumulator

__device__ __forceinline__ ushort f2bf(float f) {           // fp32 -> bf16 RNE
  union { float f; uint u; } v; v.f = f;
  uint u = v.u + 0x7fffu + ((v.u >> 16) & 1u);
  return (ushort)(u >> 16);
}
__device__ __forceinline__ float bf2f(ushort u) {
  union { uint u; float f; } v; v.u = ((uint)u) << 16;
  return v.f;
}

// ---------------------------------------------------------------------------
// histogram over segments s = dst*8 + rel   (this IS the per-(dst,rel) degree)
// ---------------------------------------------------------------------------
__global__ __launch_bounds__(256) void hist_kernel(const int* __restrict__ dst,
                                                   const int* __restrict__ et,
                                                   uint* __restrict__ hist, int E) {
  int e = blockIdx.x * 256 + threadIdx.x;
  if (e < E) atomicAdd(&hist[(size_t)dst[e] * NREL + et[e]], 1u);
}

// ---------------------------------------------------------------------------
// scan stage 1: per-block (2048 elems) sums
// ---------------------------------------------------------------------------
__global__ __launch_bounds__(256) void scan1_kernel(const uint* __restrict__ hist,
                                                    uint* __restrict__ bsum, int ns) {
  __shared__ uint r[256];
  int b = blockIdx.x, t = threadIdx.x;
  int base = b * 2048 + t * 8;
  uint s = 0;
#pragma unroll
  for (int i = 0; i < 8; ++i) { int k = base + i; if (k < ns) s += hist[k]; }
  r[t] = s; __syncthreads();
  for (int d = 128; d > 0; d >>= 1) { if (t < d) r[t] += r[t + d]; __syncthreads(); }
  if (t == 0) bsum[b] = r[0];
}

// ---------------------------------------------------------------------------
// scan stage 2: exclusive scan of block sums (single block, nb <= 512)
// ---------------------------------------------------------------------------
__global__ __launch_bounds__(512) void scan2_kernel(uint* __restrict__ bsum, int nb) {
  __shared__ uint s[512];
  int t = threadIdx.x;
  uint v = (t < nb) ? bsum[t] : 0u;
  s[t] = v;
  __syncthreads();
  for (int d = 1; d < 512; d <<= 1) {
    uint add = (t >= d) ? s[t - d] : 0u;
    __syncthreads();
    s[t] += add;
    __syncthreads();
  }
  if (t < nb) bsum[t] = s[t] - v;   // exclusive
}

// ---------------------------------------------------------------------------
// scan stage 3: write seg offsets + idg = 1/max(cnt,1)
// ---------------------------------------------------------------------------
__global__ __launch_bounds__(256) void scan3_kernel(const uint* __restrict__ hist,
                                                    const uint* __restrict__ bsum,
                                                    uint* __restrict__ off,
                                                    float* __restrict__ idg, int ns) {
  __shared__ uint ts[256];
  int b = blockIdx.x, t = threadIdx.x;
  int base = b * 2048 + t * 8;
  uint h[8]; uint sum = 0;
#pragma unroll
  for (int i = 0; i < 8; ++i) { int k = base + i; h[i] = (k < ns) ? hist[k] : 0u; sum += h[i]; }
  ts[t] = sum;
  __syncthreads();
  uint own = sum;
  for (int d = 1; d < 256; d <<= 1) {
    uint add = (t >= d) ? ts[t - d] : 0u;
    __syncthreads();
    ts[t] += add;
    __syncthreads();
  }
  uint run = bsum[b] + (ts[t] - own);
#pragma unroll
  for (int i = 0; i < 8; ++i) {
    int k = base + i;
    if (k < ns) {
      off[k] = run;
      idg[k] = 1.0f / fmaxf((float)h[i], 1.0f);
      run += h[i];
    }
  }
}

__global__ void offend_kernel(uint* __restrict__ off, int ns, int E) {
  off[ns] = (uint)E;
}

// ---------------------------------------------------------------------------
// placement: sp[off[s] + cursor] = src*8 + rel, segment-sorted
// ---------------------------------------------------------------------------
__global__ __launch_bounds__(256) void place_kernel(const int* __restrict__ src,
                                                    const int* __restrict__ dst,
                                                    const int* __restrict__ et,
                                                    const uint* __restrict__ off,
                                                    uint* __restrict__ cur,
                                                    uint* __restrict__ sp, int E) {
  int e = blockIdx.x * 256 + threadIdx.x;
  if (e >= E) return;
  int r = et[e];
  uint s = (uint)dst[e] * NREL + r;
  uint pos = off[s] + atomicAdd(&cur[s], 1u);
  sp[pos] = ((uint)src[e] << 3) | (uint)r;
}

// ---------------------------------------------------------------------------
// transpose-convert weights: out_bf16[r][n][k] = in_f32[r][k][n]
// ---------------------------------------------------------------------------
__global__ __launch_bounds__(256) void cvt_wt_kernel(const float* __restrict__ in,
                                                     ushort* __restrict__ out,
                                                     int R, int K, int N) {
  int idx = blockIdx.x * 256 + threadIdx.x;
  if (idx >= R * K * N) return;
  int r = idx / (K * N);
  int rem = idx - r * K * N;
  int n = rem / K;
  int k = rem - n * K;
  out[idx] = f2bf(in[(size_t)r * K * N + (size_t)k * N + n]);
}

// ---------------------------------------------------------------------------
// xt[m][r*64+n] = bf16( sum_k x[m][k] * W1[r][k][n] )   MFMA, swapped operands
// ---------------------------------------------------------------------------
__global__ __launch_bounds__(256) void gemm_xt_kernel(const float* __restrict__ x,
                                                      const ushort* __restrict__ W1t,
                                                      ushort* __restrict__ xt, int M) {
  __shared__ __align__(16) ushort Axs[64][136];
  __shared__ __align__(16) ushort Bws[64][136];
  const int tid = threadIdx.x;
  const int w = tid >> 6, l = tid & 63;
  const int rows0 = blockIdx.x * 64;
#pragma unroll
  for (int i = 0; i < 8; ++i) {
    int g = tid + 256 * i;
    int row = g >> 5, c4 = (g & 31) * 4;
    int rr = rows0 + row; if (rr >= M) rr = M - 1;
    float4 v = *(const float4*)&x[(size_t)rr * 128 + c4];
    *(ushort4*)&Axs[row][c4] = make_ushort4(f2bf(v.x), f2bf(v.y), f2bf(v.z), f2bf(v.w));
  }
  __syncthreads();
  const int mrow = w * 16 + (l & 15);
  const int koff = (l >> 4) * 8;
  bfrag8 xf[4];
#pragma unroll
  for (int kc = 0; kc < 4; ++kc)
    xf[kc] = *(const bfrag8*)&Axs[mrow][kc * 32 + koff];
  const int m = rows0 + mrow;
  for (int r = 0; r < NREL; ++r) {
    __syncthreads();
#pragma unroll
    for (int i = 0; i < 8; ++i) {
      int g = tid + 256 * i;
      int row = g >> 5, c4 = (g & 31) * 4;
      *(ushort4*)&Bws[row][c4] = *(const ushort4*)&W1t[((size_t)r * 64 + row) * 128 + c4];
    }
    __syncthreads();
#pragma unroll
    for (int ct = 0; ct < 4; ++ct) {
      facc4 acc = {0.f, 0.f, 0.f, 0.f};
#pragma unroll
      for (int kc = 0; kc < 4; ++kc) {
        bfrag8 af = *(const bfrag8*)&Bws[ct * 16 + (l & 15)][kc * 32 + koff];
        acc = __builtin_amdgcn_mfma_f32_16x16x32_bf16(af, xf[kc], acc, 0, 0, 0);
      }
      if (m < M) {
        int n0 = ct * 16 + (l >> 4) * 4;
        *(ushort4*)&xt[(size_t)m * 512 + r * 64 + n0] =
            make_ushort4(f2bf(acc[0]), f2bf(acc[1]), f2bf(acc[2]), f2bf(acc[3]));
      }
    }
  }
}

// ---------------------------------------------------------------------------
// agg1[d][lane] = sum_r idg[d,r] * sum_{e in seg(d,r)} xt[src_e][r][lane]
// one wave per dst, lane = feature; edges segment-sorted
// ---------------------------------------------------------------------------
__global__ __launch_bounds__(256) void agg1_kernel(const uint* __restrict__ off,
                                                   const uint* __restrict__ sp,
                                                   const float* __restrict__ idg,
                                                   const ushort* __restrict__ xt,
                                                   float* __restrict__ agg, int N) {
  int wid = (blockIdx.x * 256 + threadIdx.x) >> 6;
  if (wid >= N) return;
  int lane = threadIdx.x & 63;
  uint e0 = off[(size_t)wid * 8], e1 = off[(size_t)wid * 8 + 8];
  float acc = 0.f;
  uint e = e0;
  for (; e + 1 < e1; e += 2) {      // 2x unroll: independent gathers in flight
    uint p0 = sp[e], p1 = sp[e + 1];
    float v0 = bf2f(xt[(size_t)(p0 >> 3) * 512 + (p0 & 7u) * 64 + lane]);
    float v1 = bf2f(xt[(size_t)(p1 >> 3) * 512 + (p1 & 7u) * 64 + lane]);
    acc += v0 * idg[(size_t)wid * 8 + (p0 & 7u)];
    acc += v1 * idg[(size_t)wid * 8 + (p1 & 7u)];
  }
  if (e < e1) {
    uint p0 = sp[e];
    acc += bf2f(xt[(size_t)(p0 >> 3) * 512 + (p0 & 7u) * 64 + lane]) *
           idg[(size_t)wid * 8 + (p0 & 7u)];
  }
  agg[(size_t)wid * 64 + lane] = acc;
}

// ---------------------------------------------------------------------------
// y2[d][r][lane] = bf16( idg[d,r] * sum_{e in seg(d,r)} h[src_e][lane] )
// ---------------------------------------------------------------------------
__global__ __launch_bounds__(256) void agg2_kernel(const uint* __restrict__ off,
                                                   const uint* __restrict__ sp,
                                                   const float* __restrict__ idg,
                                                   const ushort* __restrict__ hb,
                                                   ushort* __restrict__ y2, int N) {
  int wid = (blockIdx.x * 256 + threadIdx.x) >> 6;
  if (wid >= N) return;
  int lane = threadIdx.x & 63;
#pragma unroll
  for (int r = 0; r < NREL; ++r) {
    uint e0 = off[(size_t)wid * 8 + r], e1 = off[(size_t)wid * 8 + r + 1];
    float acc = 0.f;
    for (uint e = e0; e < e1; ++e) {
      uint src = sp[e] >> 3;
      acc += bf2f(hb[(size_t)src * 64 + lane]);
    }
    y2[(size_t)wid * 512 + r * 64 + lane] = f2bf(acc * idg[(size_t)wid * 8 + r]);
  }
}

// ---------------------------------------------------------------------------
// hb[m][n] = bf16( relu( agg[m][n] + (x root1)[m][n] + b1[n] ) )
// ---------------------------------------------------------------------------
__global__ __launch_bounds__(256) void reduce_h_kernel(const float* __restrict__ x,
                                                       const ushort* __restrict__ r1t,
                                                       const float* __restrict__ b1,
                                                       const float* __restrict__ agg,
                                                       ushort* __restrict__ hb, int M) {
  __shared__ __align__(16) ushort Axs[64][136];
  __shared__ __align__(16) ushort Bws[64][136];
  const int tid = threadIdx.x;
  const int w = tid >> 6, l = tid & 63;
  const int rows0 = blockIdx.x * 64;
#pragma unroll
  for (int i = 0; i < 8; ++i) {
    int g = tid + 256 * i;
    int row = g >> 5, c4 = (g & 31) * 4;
    int rr = rows0 + row; if (rr >= M) rr = M - 1;
    float4 v = *(const float4*)&x[(size_t)rr * 128 + c4];
    *(ushort4*)&Axs[row][c4] = make_ushort4(f2bf(v.x), f2bf(v.y), f2bf(v.z), f2bf(v.w));
    *(ushort4*)&Bws[row][c4] = *(const ushort4*)&r1t[(size_t)row * 128 + c4];
  }
  __syncthreads();
  const int mrow = w * 16 + (l & 15);
  const int koff = (l >> 4) * 8;
  const int m = rows0 + mrow;
  const int mc = (m < M) ? m : (M - 1);
  bfrag8 xf[4];
#pragma unroll
  for (int kc = 0; kc < 4; ++kc)
    xf[kc] = *(const bfrag8*)&Axs[mrow][kc * 32 + koff];
  facc4 acc[4] = {};
#pragma unroll
  for (int ct = 0; ct < 4; ++ct)
#pragma unroll
    for (int kc = 0; kc < 4; ++kc) {
      bfrag8 af = *(const bfrag8*)&Bws[ct * 16 + (l & 15)][kc * 32 + koff];
      acc[ct] = __builtin_amdgcn_mfma_f32_16x16x32_bf16(af, xf[kc], acc[ct], 0, 0, 0);
    }
#pragma unroll
  for (int ct = 0; ct < 4; ++ct) {
    int n0 = ct * 16 + (l >> 4) * 4;
    float4 s4 = *(const float4*)&agg[(size_t)mc * 64 + n0];
    float4 bb = *(const float4*)&b1[n0];
    float h0 = fmaxf(acc[ct][0] + s4.x + bb.x, 0.f);
    float h1 = fmaxf(acc[ct][1] + s4.y + bb.y, 0.f);
    float h2 = fmaxf(acc[ct][2] + s4.z + bb.z, 0.f);
    float h3 = fmaxf(acc[ct][3] + s4.w + bb.w, 0.f);
    if (m < M)
      *(ushort4*)&hb[(size_t)m * 64 + n0] =
          make_ushort4(f2bf(h0), f2bf(h1), f2bf(h2), f2bf(h3));
  }
}

// ---------------------------------------------------------------------------
// out[m][n] = sum_r y2[m][r][:] W2[r][:][n] + (h root2)[m][n] + b2[n]
// (y2 pre-normalized)
// ---------------------------------------------------------------------------
__global__ __launch_bounds__(256) void gemm_out_kernel(const ushort* __restrict__ hb,
                                                       const ushort* __restrict__ y2,
                                                       const ushort* __restrict__ W2t,
                                                       const ushort* __restrict__ r2t,
                                                       const float* __restrict__ b2,
                                                       float* __restrict__ out, int M) {
  __shared__ __align__(16) ushort Bws[128][72];
  const int tid = threadIdx.x;
  const int w = tid >> 6, l = tid & 63;
  const int rows0 = blockIdx.x * 64;
  const int mrow = w * 16 + (l & 15);
  const int koff = (l >> 4) * 8;
  const int m = rows0 + mrow;
  const int mc = (m < M) ? m : (M - 1);
  facc4 oacc[8] = {};
  // ---- root2 part ----
#pragma unroll
  for (int i = 0; i < 8; ++i) {
    int g = tid + 256 * i;
    int row = g >> 4, c4 = (g & 15) * 4;
    *(ushort4*)&Bws[row][c4] = *(const ushort4*)&r2t[(size_t)row * 64 + c4];
  }
  __syncthreads();
  {
    bfrag8 h0 = *(const bfrag8*)&hb[(size_t)mc * 64 + koff];
    bfrag8 h1 = *(const bfrag8*)&hb[(size_t)mc * 64 + 32 + koff];
#pragma unroll
    for (int ct = 0; ct < 8; ++ct) {
      bfrag8 a0 = *(const bfrag8*)&Bws[ct * 16 + (l & 15)][koff];
      bfrag8 a1 = *(const bfrag8*)&Bws[ct * 16 + (l & 15)][32 + koff];
      oacc[ct] = __builtin_amdgcn_mfma_f32_16x16x32_bf16(a0, h0, oacc[ct], 0, 0, 0);
      oacc[ct] = __builtin_amdgcn_mfma_f32_16x16x32_bf16(a1, h1, oacc[ct], 0, 0, 0);
    }
  }
  // ---- relation parts (y2 already normalized) ----
  for (int r = 0; r < NREL; ++r) {
    __syncthreads();
#pragma unroll
    for (int i = 0; i < 8; ++i) {
      int g = tid + 256 * i;
      int row = g >> 4, c4 = (g & 15) * 4;
      *(ushort4*)&Bws[row][c4] = *(const ushort4*)&W2t[((size_t)r * 128 + row) * 64 + c4];
    }
    __syncthreads();
    bfrag8 y0 = *(const bfrag8*)&y2[(size_t)mc * 512 + r * 64 + koff];
    bfrag8 y1f = *(const bfrag8*)&y2[(size_t)mc * 512 + r * 64 + 32 + koff];
#pragma unroll
    for (int ct = 0; ct < 8; ++ct) {
      bfrag8 a0 = *(const bfrag8*)&Bws[ct * 16 + (l & 15)][koff];
      bfrag8 a1 = *(const bfrag8*)&Bws[ct * 16 + (l & 15)][32 + koff];
      oacc[ct] = __builtin_amdgcn_mfma_f32_16x16x32_bf16(a0, y0, oacc[ct], 0, 0, 0);
      oacc[ct] = __builtin_amdgcn_mfma_f32_16x16x32_bf16(a1, y1f, oacc[ct], 0, 0, 0);
    }
  }
  if (m < M) {
#pragma unroll
    for (int ct = 0; ct < 8; ++ct) {
      int n0 = ct * 16 + (l >> 4) * 4;
      float4 bb = *(const float4*)&b2[n0];
      float4 o = make_float4(oacc[ct][0] + bb.x, oacc[ct][1] + bb.y,
                             oacc[ct][2] + bb.z, oacc[ct][3] + bb.w);
      *(float4*)&out[(size_t)m * 128 + n0] = o;
    }
  }
}

// ---------------------------------------------------------------------------
extern "C" void kernel_launch(void* const* d_in, const int* in_sizes, int n_in,
                              void* d_out, int out_size, void* d_ws, size_t ws_size,
                              hipStream_t stream) {
  const float* x     = (const float*)d_in[0];
  const int*   ei    = (const int*)d_in[1];
  const int*   et    = (const int*)d_in[2];
  const float* W1    = (const float*)d_in[3];
  const float* root1 = (const float*)d_in[4];
  const float* b1    = (const float*)d_in[5];
  const float* W2    = (const float*)d_in[6];
  const float* root2 = (const float*)d_in[7];
  const float* b2    = (const float*)d_in[8];
  float* out = (float*)d_out;

  const int M = in_sizes[0] / 128;   // 100000
  const int E = in_sizes[2];         // 1600000
  const int NS = M * NREL;           // segments
  const int* srcp = ei;
  const int* dstp = ei + E;

  auto align = [](char*& p, size_t n) { char* q = p; p += (n + 255) & ~(size_t)255; return q; };
  char* p = (char*)d_ws;
  ushort* xt   = (ushort*)align(p, (size_t)M * 512 * 2);  // layer1 xt / layer2 y2 (alias)
  float*  agg  = (float*) align(p, (size_t)M * 64 * 4);
  ushort* hb   = (ushort*)align(p, (size_t)M * 64 * 2);
  uint*   hist = (uint*)  align(p, (size_t)NS * 4);
  uint*   cur  = (uint*)  align(p, (size_t)NS * 4);
  uint*   off  = (uint*)  align(p, (size_t)(NS + 1) * 4);
  float*  idg  = (float*) align(p, (size_t)NS * 4);
  uint*   sp   = (uint*)  align(p, (size_t)E * 4);
  uint*   bsum = (uint*)  align(p, 4096);
  ushort* W1t  = (ushort*)align(p, (size_t)NREL * 64 * 128 * 2);
  ushort* r1t  = (ushort*)align(p, (size_t)64 * 128 * 2);
  ushort* W2t  = (ushort*)align(p, (size_t)NREL * 128 * 64 * 2);
  ushort* r2t  = (ushort*)align(p, (size_t)128 * 64 * 2);
  ushort* y2 = xt;

  // tiny weight transpose-converts
  cvt_wt_kernel<<<(NREL * 128 * 64 + 255) / 256, 256, 0, stream>>>(W1, W1t, NREL, 128, 64);
  cvt_wt_kernel<<<(128 * 64 + 255) / 256, 256, 0, stream>>>(root1, r1t, 1, 128, 64);
  cvt_wt_kernel<<<(NREL * 64 * 128 + 255) / 256, 256, 0, stream>>>(W2, W2t, NREL, 64, 128);
  cvt_wt_kernel<<<(64 * 128 + 255) / 256, 256, 0, stream>>>(root2, r2t, 1, 64, 128);

  // ---- counting sort by (dst, rel) ----
  hipMemsetAsync(hist, 0, (size_t)NS * 4, stream);
  hipMemsetAsync(cur, 0, (size_t)NS * 4, stream);
  hist_kernel<<<(E + 255) / 256, 256, 0, stream>>>(dstp, et, hist, E);
  const int NB = (NS + 2047) / 2048;
  scan1_kernel<<<NB, 256, 0, stream>>>(hist, bsum, NS);
  scan2_kernel<<<1, 512, 0, stream>>>(bsum, NB);
  scan3_kernel<<<NB, 256, 0, stream>>>(hist, bsum, off, idg, NS);
  offend_kernel<<<1, 1, 0, stream>>>(off, NS, E);
  place_kernel<<<(E + 255) / 256, 256, 0, stream>>>(srcp, dstp, et, off, cur, sp, E);

  const int MB64 = (M + 63) / 64;
  const int AGB = (M * 64 + 255) / 256;   // one wave per dst

  // ---- layer 1: transform -> sorted gather-aggregate -> root+relu ----
  gemm_xt_kernel<<<MB64, 256, 0, stream>>>(x, W1t, xt, M);
  agg1_kernel<<<AGB, 256, 0, stream>>>(off, sp, idg, xt, agg, M);
  reduce_h_kernel<<<MB64, 256, 0, stream>>>(x, r1t, b1, agg, hb, M);

  // ---- layer 2: sorted gather-aggregate (pre-normalized) -> fused GEMM ----
  agg2_kernel<<<AGB, 256, 0, stream>>>(off, sp, idg, hb, y2, M);
  gemm_out_kernel<<<MB64, 256, 0, stream>>>(hb, y2, W2t, r2t, b2, out, M);
}

// Round 4
// 410.164 us; speedup vs baseline: 3.7315x; 1.3229x over previous
//
#include <hip/hip_runtime.h>
#include <cstdint>
#include <cstddef>

#define NREL 8

typedef __attribute__((ext_vector_type(8))) short bfrag8;   // 8 bf16 (4 VGPR)
typedef __attribute__((ext_vector_type(4))) float facc4;    // mfma accumulator

__device__ __forceinline__ ushort f2bf(float f) {           // fp32 -> bf16 RNE
  union { float f; uint u; } v; v.f = f;
  uint u = v.u + 0x7fffu + ((v.u >> 16) & 1u);
  return (ushort)(u >> 16);
}
__device__ __forceinline__ float bf2f(ushort u) {
  union { uint u; float f; } v; v.u = ((uint)u) << 16;
  return v.f;
}

// ---------------------------------------------------------------------------
// histogram over segments s = dst*8 + rel   (this IS the per-(dst,rel) degree)
// ---------------------------------------------------------------------------
__global__ __launch_bounds__(256) void hist_kernel(const int* __restrict__ dst,
                                                   const int* __restrict__ et,
                                                   uint* __restrict__ hist, int E) {
  int e = blockIdx.x * 256 + threadIdx.x;
  if (e < E) atomicAdd(&hist[(size_t)dst[e] * NREL + et[e]], 1u);
}

// ---------------------------------------------------------------------------
// scan stage 1: per-block (2048 elems) sums
// ---------------------------------------------------------------------------
__global__ __launch_bounds__(256) void scan1_kernel(const uint* __restrict__ hist,
                                                    uint* __restrict__ bsum, int ns) {
  __shared__ uint r[256];
  int b = blockIdx.x, t = threadIdx.x;
  int base = b * 2048 + t * 8;
  uint s = 0;
#pragma unroll
  for (int i = 0; i < 8; ++i) { int k = base + i; if (k < ns) s += hist[k]; }
  r[t] = s; __syncthreads();
  for (int d = 128; d > 0; d >>= 1) { if (t < d) r[t] += r[t + d]; __syncthreads(); }
  if (t == 0) bsum[b] = r[0];
}

// ---------------------------------------------------------------------------
// scan stage 2: exclusive scan of block sums (single block, nb <= 512)
// ---------------------------------------------------------------------------
__global__ __launch_bounds__(512) void scan2_kernel(uint* __restrict__ bsum, int nb) {
  __shared__ uint s[512];
  int t = threadIdx.x;
  uint v = (t < nb) ? bsum[t] : 0u;
  s[t] = v;
  __syncthreads();
  for (int d = 1; d < 512; d <<= 1) {
    uint add = (t >= d) ? s[t - d] : 0u;
    __syncthreads();
    s[t] += add;
    __syncthreads();
  }
  if (t < nb) bsum[t] = s[t] - v;   // exclusive
}

// ---------------------------------------------------------------------------
// scan stage 3: write seg offsets + idg = 1/max(cnt,1)
// ---------------------------------------------------------------------------
__global__ __launch_bounds__(256) void scan3_kernel(const uint* __restrict__ hist,
                                                    const uint* __restrict__ bsum,
                                                    uint* __restrict__ off,
                                                    float* __restrict__ idg, int ns) {
  __shared__ uint ts[256];
  int b = blockIdx.x, t = threadIdx.x;
  int base = b * 2048 + t * 8;
  uint h[8]; uint sum = 0;
#pragma unroll
  for (int i = 0; i < 8; ++i) { int k = base + i; h[i] = (k < ns) ? hist[k] : 0u; sum += h[i]; }
  ts[t] = sum;
  __syncthreads();
  uint own = sum;
  for (int d = 1; d < 256; d <<= 1) {
    uint add = (t >= d) ? ts[t - d] : 0u;
    __syncthreads();
    ts[t] += add;
    __syncthreads();
  }
  uint run = bsum[b] + (ts[t] - own);
#pragma unroll
  for (int i = 0; i < 8; ++i) {
    int k = base + i;
    if (k < ns) {
      off[k] = run;
      idg[k] = 1.0f / fmaxf((float)h[i], 1.0f);
      run += h[i];
    }
  }
}

__global__ void offend_kernel(uint* __restrict__ off, int ns, int E) {
  off[ns] = (uint)E;
}

// ---------------------------------------------------------------------------
// placement: sp[off[s] + cursor] = src*8 + rel, segment-sorted
// ---------------------------------------------------------------------------
__global__ __launch_bounds__(256) void place_kernel(const int* __restrict__ src,
                                                    const int* __restrict__ dst,
                                                    const int* __restrict__ et,
                                                    const uint* __restrict__ off,
                                                    uint* __restrict__ cur,
                                                    uint* __restrict__ sp, int E) {
  int e = blockIdx.x * 256 + threadIdx.x;
  if (e >= E) return;
  int r = et[e];
  uint s = (uint)dst[e] * NREL + r;
  uint pos = off[s] + atomicAdd(&cur[s], 1u);
  sp[pos] = ((uint)src[e] << 3) | (uint)r;
}

// ---------------------------------------------------------------------------
// transpose-convert weights: out_bf16[r][n][k] = in_f32[r][k][n]
// ---------------------------------------------------------------------------
__global__ __launch_bounds__(256) void cvt_wt_kernel(const float* __restrict__ in,
                                                     ushort* __restrict__ out,
                                                     int R, int K, int N) {
  int idx = blockIdx.x * 256 + threadIdx.x;
  if (idx >= R * K * N) return;
  int r = idx / (K * N);
  int rem = idx - r * K * N;
  int n = rem / K;
  int k = rem - n * K;
  out[idx] = f2bf(in[(size_t)r * K * N + (size_t)k * N + n]);
}

// ---------------------------------------------------------------------------
// xt[m][r*64+n] = bf16( sum_k x[m][k] * W1[r][k][n] )   MFMA, swapped operands
// ---------------------------------------------------------------------------
__global__ __launch_bounds__(256) void gemm_xt_kernel(const float* __restrict__ x,
                                                      const ushort* __restrict__ W1t,
                                                      ushort* __restrict__ xt, int M) {
  __shared__ __align__(16) ushort Axs[64][136];
  __shared__ __align__(16) ushort Bws[64][136];
  const int tid = threadIdx.x;
  const int w = tid >> 6, l = tid & 63;
  const int rows0 = blockIdx.x * 64;
#pragma unroll
  for (int i = 0; i < 8; ++i) {
    int g = tid + 256 * i;
    int row = g >> 5, c4 = (g & 31) * 4;
    int rr = rows0 + row; if (rr >= M) rr = M - 1;
    float4 v = *(const float4*)&x[(size_t)rr * 128 + c4];
    *(ushort4*)&Axs[row][c4] = make_ushort4(f2bf(v.x), f2bf(v.y), f2bf(v.z), f2bf(v.w));
  }
  __syncthreads();
  const int mrow = w * 16 + (l & 15);
  const int koff = (l >> 4) * 8;
  bfrag8 xf[4];
#pragma unroll
  for (int kc = 0; kc < 4; ++kc)
    xf[kc] = *(const bfrag8*)&Axs[mrow][kc * 32 + koff];
  const int m = rows0 + mrow;
  for (int r = 0; r < NREL; ++r) {
    __syncthreads();
#pragma unroll
    for (int i = 0; i < 8; ++i) {
      int g = tid + 256 * i;
      int row = g >> 5, c4 = (g & 31) * 4;
      *(ushort4*)&Bws[row][c4] = *(const ushort4*)&W1t[((size_t)r * 64 + row) * 128 + c4];
    }
    __syncthreads();
#pragma unroll
    for (int ct = 0; ct < 4; ++ct) {
      facc4 acc = {0.f, 0.f, 0.f, 0.f};
#pragma unroll
      for (int kc = 0; kc < 4; ++kc) {
        bfrag8 af = *(const bfrag8*)&Bws[ct * 16 + (l & 15)][kc * 32 + koff];
        acc = __builtin_amdgcn_mfma_f32_16x16x32_bf16(af, xf[kc], acc, 0, 0, 0);
      }
      if (m < M) {
        int n0 = ct * 16 + (l >> 4) * 4;
        *(ushort4*)&xt[(size_t)m * 512 + r * 64 + n0] =
            make_ushort4(f2bf(acc[0]), f2bf(acc[1]), f2bf(acc[2]), f2bf(acc[3]));
      }
    }
  }
}

// ---------------------------------------------------------------------------
// agg1[d][lane] = sum_r idg[d,r] * sum_{e in seg(d,r)} xt[src_e][r][lane]
// one wave per dst; sp batch-loaded via lanes + shfl; gathers pipelined x8
// ---------------------------------------------------------------------------
__global__ __launch_bounds__(256) void agg1_kernel(const uint* __restrict__ off,
                                                   const uint* __restrict__ sp,
                                                   const float* __restrict__ idg,
                                                   const ushort* __restrict__ xt,
                                                   float* __restrict__ agg, int N, int E) {
  int wid = (blockIdx.x * 256 + threadIdx.x) >> 6;
  if (wid >= N) return;
  int lane = threadIdx.x & 63;
  uint e0 = off[(size_t)wid * 8], e1 = off[(size_t)wid * 8 + 8];
  float idgl = (lane < 8) ? idg[(size_t)wid * 8 + lane] : 0.f;
  float acc = 0.f;
  for (uint b0 = e0; b0 < e1; b0 += 64) {
    uint vsp = (b0 + (uint)lane < (uint)E) ? sp[b0 + lane] : 0u;
    int n = min(64, (int)(e1 - b0));
    int i = 0;
    for (; i + 8 <= n; i += 8) {
      uint p[8]; float v[8];
#pragma unroll
      for (int j = 0; j < 8; ++j) p[j] = __shfl(vsp, i + j);
#pragma unroll
      for (int j = 0; j < 8; ++j)
        v[j] = bf2f(xt[(size_t)(p[j] >> 3) * 512 + (p[j] & 7u) * 64 + lane]);
#pragma unroll
      for (int j = 0; j < 8; ++j)
        acc += v[j] * __shfl(idgl, (int)(p[j] & 7u));
    }
    for (; i < n; ++i) {
      uint pp = __shfl(vsp, i);
      acc += bf2f(xt[(size_t)(pp >> 3) * 512 + (pp & 7u) * 64 + lane]) *
             __shfl(idgl, (int)(pp & 7u));
    }
  }
  agg[(size_t)wid * 64 + lane] = acc;
}

// ---------------------------------------------------------------------------
// y2[d][r][lane] = bf16( idg[d,r] * sum_{e in seg(d,r)} h[src_e][lane] )
// flat edge loop, pipelined gathers x8, wave-uniform flush on rel change
// ---------------------------------------------------------------------------
__global__ __launch_bounds__(256) void agg2_kernel(const uint* __restrict__ off,
                                                   const uint* __restrict__ sp,
                                                   const float* __restrict__ idg,
                                                   const ushort* __restrict__ hb,
                                                   ushort* __restrict__ y2, int N, int E) {
  int wid = (blockIdx.x * 256 + threadIdx.x) >> 6;
  if (wid >= N) return;
  int lane = threadIdx.x & 63;
  uint e0 = off[(size_t)wid * 8], e1 = off[(size_t)wid * 8 + 8];
  float idgl = (lane < 8) ? idg[(size_t)wid * 8 + lane] : 0.f;
  float acc = 0.f;
  int curR = -1;
  uint written = 0;
  for (uint b0 = e0; b0 < e1; b0 += 64) {
    uint vsp = (b0 + (uint)lane < (uint)E) ? sp[b0 + lane] : 0u;
    int n = min(64, (int)(e1 - b0));
    int i = 0;
    for (; i + 8 <= n; i += 8) {
      uint p[8]; float v[8];
#pragma unroll
      for (int j = 0; j < 8; ++j) p[j] = __shfl(vsp, i + j);
#pragma unroll
      for (int j = 0; j < 8; ++j)
        v[j] = bf2f(hb[(size_t)(p[j] >> 3) * 64 + lane]);
#pragma unroll
      for (int j = 0; j < 8; ++j) {
        int r = (int)(p[j] & 7u);
        if (r != curR) {                 // wave-uniform (p from shfl)
          if (curR >= 0) {
            y2[(size_t)wid * 512 + curR * 64 + lane] = f2bf(acc * __shfl(idgl, curR));
            written |= 1u << curR;
          }
          acc = 0.f; curR = r;
        }
        acc += v[j];
      }
    }
    for (; i < n; ++i) {
      uint pp = __shfl(vsp, i);
      int r = (int)(pp & 7u);
      if (r != curR) {
        if (curR >= 0) {
          y2[(size_t)wid * 512 + curR * 64 + lane] = f2bf(acc * __shfl(idgl, curR));
          written |= 1u << curR;
        }
        acc = 0.f; curR = r;
      }
      acc += bf2f(hb[(size_t)(pp >> 3) * 64 + lane]);
    }
  }
  if (curR >= 0) {
    y2[(size_t)wid * 512 + curR * 64 + lane] = f2bf(acc * __shfl(idgl, curR));
    written |= 1u << curR;
  }
#pragma unroll
  for (int r = 0; r < 8; ++r)
    if (!((written >> r) & 1u))
      y2[(size_t)wid * 512 + r * 64 + lane] = 0;
}

// ---------------------------------------------------------------------------
// hb[m][n] = bf16( relu( agg[m][n] + (x root1)[m][n] + b1[n] ) )
// ---------------------------------------------------------------------------
__global__ __launch_bounds__(256) void reduce_h_kernel(const float* __restrict__ x,
                                                       const ushort* __restrict__ r1t,
                                                       const float* __restrict__ b1,
                                                       const float* __restrict__ agg,
                                                       ushort* __restrict__ hb, int M) {
  __shared__ __align__(16) ushort Axs[64][136];
  __shared__ __align__(16) ushort Bws[64][136];
  const int tid = threadIdx.x;
  const int w = tid >> 6, l = tid & 63;
  const int rows0 = blockIdx.x * 64;
#pragma unroll
  for (int i = 0; i < 8; ++i) {
    int g = tid + 256 * i;
    int row = g >> 5, c4 = (g & 31) * 4;
    int rr = rows0 + row; if (rr >= M) rr = M - 1;
    float4 v = *(const float4*)&x[(size_t)rr * 128 + c4];
    *(ushort4*)&Axs[row][c4] = make_ushort4(f2bf(v.x), f2bf(v.y), f2bf(v.z), f2bf(v.w));
    *(ushort4*)&Bws[row][c4] = *(const ushort4*)&r1t[(size_t)row * 128 + c4];
  }
  __syncthreads();
  const int mrow = w * 16 + (l & 15);
  const int koff = (l >> 4) * 8;
  const int m = rows0 + mrow;
  const int mc = (m < M) ? m : (M - 1);
  bfrag8 xf[4];
#pragma unroll
  for (int kc = 0; kc < 4; ++kc)
    xf[kc] = *(const bfrag8*)&Axs[mrow][kc * 32 + koff];
  facc4 acc[4] = {};
#pragma unroll
  for (int ct = 0; ct < 4; ++ct)
#pragma unroll
    for (int kc = 0; kc < 4; ++kc) {
      bfrag8 af = *(const bfrag8*)&Bws[ct * 16 + (l & 15)][kc * 32 + koff];
      acc[ct] = __builtin_amdgcn_mfma_f32_16x16x32_bf16(af, xf[kc], acc[ct], 0, 0, 0);
    }
#pragma unroll
  for (int ct = 0; ct < 4; ++ct) {
    int n0 = ct * 16 + (l >> 4) * 4;
    float4 s4 = *(const float4*)&agg[(size_t)mc * 64 + n0];
    float4 bb = *(const float4*)&b1[n0];
    float h0 = fmaxf(acc[ct][0] + s4.x + bb.x, 0.f);
    float h1 = fmaxf(acc[ct][1] + s4.y + bb.y, 0.f);
    float h2 = fmaxf(acc[ct][2] + s4.z + bb.z, 0.f);
    float h3 = fmaxf(acc[ct][3] + s4.w + bb.w, 0.f);
    if (m < M)
      *(ushort4*)&hb[(size_t)m * 64 + n0] =
          make_ushort4(f2bf(h0), f2bf(h1), f2bf(h2), f2bf(h3));
  }
}

// ---------------------------------------------------------------------------
// out[m][n] = sum_r y2[m][r][:] W2[r][:][n] + (h root2)[m][n] + b2[n]
// (y2 pre-normalized)
// ---------------------------------------------------------------------------
__global__ __launch_bounds__(256) void gemm_out_kernel(const ushort* __restrict__ hb,
                                                       const ushort* __restrict__ y2,
                                                       const ushort* __restrict__ W2t,
                                                       const ushort* __restrict__ r2t,
                                                       const float* __restrict__ b2,
                                                       float* __restrict__ out, int M) {
  __shared__ __align__(16) ushort Bws[128][72];
  const int tid = threadIdx.x;
  const int w = tid >> 6, l = tid & 63;
  const int rows0 = blockIdx.x * 64;
  const int mrow = w * 16 + (l & 15);
  const int koff = (l >> 4) * 8;
  const int m = rows0 + mrow;
  const int mc = (m < M) ? m : (M - 1);
  facc4 oacc[8] = {};
  // ---- root2 part ----
#pragma unroll
  for (int i = 0; i < 8; ++i) {
    int g = tid + 256 * i;
    int row = g >> 4, c4 = (g & 15) * 4;
    *(ushort4*)&Bws[row][c4] = *(const ushort4*)&r2t[(size_t)row * 64 + c4];
  }
  __syncthreads();
  {
    bfrag8 h0 = *(const bfrag8*)&hb[(size_t)mc * 64 + koff];
    bfrag8 h1 = *(const bfrag8*)&hb[(size_t)mc * 64 + 32 + koff];
#pragma unroll
    for (int ct = 0; ct < 8; ++ct) {
      bfrag8 a0 = *(const bfrag8*)&Bws[ct * 16 + (l & 15)][koff];
      bfrag8 a1 = *(const bfrag8*)&Bws[ct * 16 + (l & 15)][32 + koff];
      oacc[ct] = __builtin_amdgcn_mfma_f32_16x16x32_bf16(a0, h0, oacc[ct], 0, 0, 0);
      oacc[ct] = __builtin_amdgcn_mfma_f32_16x16x32_bf16(a1, h1, oacc[ct], 0, 0, 0);
    }
  }
  // ---- relation parts (y2 already normalized) ----
  for (int r = 0; r < NREL; ++r) {
    __syncthreads();
#pragma unroll
    for (int i = 0; i < 8; ++i) {
      int g = tid + 256 * i;
      int row = g >> 4, c4 = (g & 15) * 4;
      *(ushort4*)&Bws[row][c4] = *(const ushort4*)&W2t[((size_t)r * 128 + row) * 64 + c4];
    }
    __syncthreads();
    bfrag8 y0 = *(const bfrag8*)&y2[(size_t)mc * 512 + r * 64 + koff];
    bfrag8 y1f = *(const bfrag8*)&y2[(size_t)mc * 512 + r * 64 + 32 + koff];
#pragma unroll
    for (int ct = 0; ct < 8; ++ct) {
      bfrag8 a0 = *(const bfrag8*)&Bws[ct * 16 + (l & 15)][koff];
      bfrag8 a1 = *(const bfrag8*)&Bws[ct * 16 + (l & 15)][32 + koff];
      oacc[ct] = __builtin_amdgcn_mfma_f32_16x16x32_bf16(a0, y0, oacc[ct], 0, 0, 0);
      oacc[ct] = __builtin_amdgcn_mfma_f32_16x16x32_bf16(a1, y1f, oacc[ct], 0, 0, 0);
    }
  }
  if (m < M) {
#pragma unroll
    for (int ct = 0; ct < 8; ++ct) {
      int n0 = ct * 16 + (l >> 4) * 4;
      float4 bb = *(const float4*)&b2[n0];
      float4 o = make_float4(oacc[ct][0] + bb.x, oacc[ct][1] + bb.y,
                             oacc[ct][2] + bb.z, oacc[ct][3] + bb.w);
      *(float4*)&out[(size_t)m * 128 + n0] = o;
    }
  }
}

// ---------------------------------------------------------------------------
extern "C" void kernel_launch(void* const* d_in, const int* in_sizes, int n_in,
                              void* d_out, int out_size, void* d_ws, size_t ws_size,
                              hipStream_t stream) {
  const float* x     = (const float*)d_in[0];
  const int*   ei    = (const int*)d_in[1];
  const int*   et    = (const int*)d_in[2];
  const float* W1    = (const float*)d_in[3];
  const float* root1 = (const float*)d_in[4];
  const float* b1    = (const float*)d_in[5];
  const float* W2    = (const float*)d_in[6];
  const float* root2 = (const float*)d_in[7];
  const float* b2    = (const float*)d_in[8];
  float* out = (float*)d_out;

  const int M = in_sizes[0] / 128;   // 100000
  const int E = in_sizes[2];         // 1600000
  const int NS = M * NREL;           // segments
  const int* srcp = ei;
  const int* dstp = ei + E;

  auto align = [](char*& p, size_t n) { char* q = p; p += (n + 255) & ~(size_t)255; return q; };
  char* p = (char*)d_ws;
  ushort* xt   = (ushort*)align(p, (size_t)M * 512 * 2);  // layer1 xt / layer2 y2 (alias)
  float*  agg  = (float*) align(p, (size_t)M * 64 * 4);
  ushort* hb   = (ushort*)align(p, (size_t)M * 64 * 2);
  uint*   hist = (uint*)  align(p, (size_t)NS * 4);
  uint*   cur  = (uint*)  align(p, (size_t)NS * 4);
  uint*   off  = (uint*)  align(p, (size_t)(NS + 1) * 4);
  float*  idg  = (float*) align(p, (size_t)NS * 4);
  uint*   sp   = (uint*)  align(p, (size_t)E * 4);
  uint*   bsum = (uint*)  align(p, 4096);
  ushort* W1t  = (ushort*)align(p, (size_t)NREL * 64 * 128 * 2);
  ushort* r1t  = (ushort*)align(p, (size_t)64 * 128 * 2);
  ushort* W2t  = (ushort*)align(p, (size_t)NREL * 128 * 64 * 2);
  ushort* r2t  = (ushort*)align(p, (size_t)128 * 64 * 2);
  ushort* y2 = xt;

  // tiny weight transpose-converts
  cvt_wt_kernel<<<(NREL * 128 * 64 + 255) / 256, 256, 0, stream>>>(W1, W1t, NREL, 128, 64);
  cvt_wt_kernel<<<(128 * 64 + 255) / 256, 256, 0, stream>>>(root1, r1t, 1, 128, 64);
  cvt_wt_kernel<<<(NREL * 64 * 128 + 255) / 256, 256, 0, stream>>>(W2, W2t, NREL, 64, 128);
  cvt_wt_kernel<<<(64 * 128 + 255) / 256, 256, 0, stream>>>(root2, r2t, 1, 64, 128);

  // ---- counting sort by (dst, rel) ----
  hipMemsetAsync(hist, 0, (size_t)NS * 4, stream);
  hipMemsetAsync(cur, 0, (size_t)NS * 4, stream);
  hist_kernel<<<(E + 255) / 256, 256, 0, stream>>>(dstp, et, hist, E);
  const int NB = (NS + 2047) / 2048;
  scan1_kernel<<<NB, 256, 0, stream>>>(hist, bsum, NS);
  scan2_kernel<<<1, 512, 0, stream>>>(bsum, NB);
  scan3_kernel<<<NB, 256, 0, stream>>>(hist, bsum, off, idg, NS);
  offend_kernel<<<1, 1, 0, stream>>>(off, NS, E);
  place_kernel<<<(E + 255) / 256, 256, 0, stream>>>(srcp, dstp, et, off, cur, sp, E);

  const int MB64 = (M + 63) / 64;
  const int AGB = (M * 64 + 255) / 256;   // one wave per dst

  // ---- layer 1: transform -> sorted gather-aggregate -> root+relu ----
  gemm_xt_kernel<<<MB64, 256, 0, stream>>>(x, W1t, xt, M);
  agg1_kernel<<<AGB, 256, 0, stream>>>(off, sp, idg, xt, agg, M, E);
  reduce_h_kernel<<<MB64, 256, 0, stream>>>(x, r1t, b1, agg, hb, M);

  // ---- layer 2: sorted gather-aggregate (pre-normalized) -> fused GEMM ----
  agg2_kernel<<<AGB, 256, 0, stream>>>(off, sp, idg, hb, y2, M, E);
  gemm_out_kernel<<<MB64, 256, 0, stream>>>(hb, y2, W2t, r2t, b2, out, M);
}

// Round 5
// 369.308 us; speedup vs baseline: 4.1443x; 1.1106x over previous
//
#include <hip/hip_runtime.h>
#include <cstdint>
#include <cstddef>

#define NREL 8

typedef __attribute__((ext_vector_type(8))) short bfrag8;   // 8 bf16 (4 VGPR)
typedef __attribute__((ext_vector_type(4))) float facc4;    // mfma accumulator

__device__ __forceinline__ ushort f2bf(float f) {           // fp32 -> bf16 RNE
  union { float f; uint u; } v; v.f = f;
  uint u = v.u + 0x7fffu + ((v.u >> 16) & 1u);
  return (ushort)(u >> 16);
}
__device__ __forceinline__ float bf2f(ushort u) {
  union { uint u; float f; } v; v.u = ((uint)u) << 16;
  return v.f;
}

// ---------------------------------------------------------------------------
// histogram over segments s = dst*8 + rel, AND per-edge rank within segment.
// 8 edges/thread, batched loads, 8 independent atomic chains.
// ---------------------------------------------------------------------------
__global__ __launch_bounds__(256) void hist_kernel(const int* __restrict__ dst,
                                                   const int* __restrict__ et,
                                                   uint* __restrict__ hist,
                                                   uint* __restrict__ rank, int E) {
  int base = (blockIdx.x * 256 + threadIdx.x) * 8;
  if (base + 8 <= E) {
    int4 d0 = *(const int4*)&dst[base], d1 = *(const int4*)&dst[base + 4];
    int4 r0 = *(const int4*)&et[base],  r1 = *(const int4*)&et[base + 4];
    int dd[8] = {d0.x, d0.y, d0.z, d0.w, d1.x, d1.y, d1.z, d1.w};
    int rr[8] = {r0.x, r0.y, r0.z, r0.w, r1.x, r1.y, r1.z, r1.w};
    uint rk[8];
#pragma unroll
    for (int j = 0; j < 8; ++j)
      rk[j] = atomicAdd(&hist[(size_t)dd[j] * NREL + rr[j]], 1u);
    uint4 o0 = make_uint4(rk[0], rk[1], rk[2], rk[3]);
    uint4 o1 = make_uint4(rk[4], rk[5], rk[6], rk[7]);
    *(uint4*)&rank[base] = o0;
    *(uint4*)&rank[base + 4] = o1;
  } else {
    for (int j = 0; base + j < E; ++j)
      rank[base + j] = atomicAdd(&hist[(size_t)dst[base + j] * NREL + et[base + j]], 1u);
  }
}

// ---------------------------------------------------------------------------
// scan stage 1: per-block (2048 elems) sums
// ---------------------------------------------------------------------------
__global__ __launch_bounds__(256) void scan1_kernel(const uint* __restrict__ hist,
                                                    uint* __restrict__ bsum, int ns) {
  __shared__ uint r[256];
  int b = blockIdx.x, t = threadIdx.x;
  int base = b * 2048 + t * 8;
  uint s = 0;
#pragma unroll
  for (int i = 0; i < 8; ++i) { int k = base + i; if (k < ns) s += hist[k]; }
  r[t] = s; __syncthreads();
  for (int d = 128; d > 0; d >>= 1) { if (t < d) r[t] += r[t + d]; __syncthreads(); }
  if (t == 0) bsum[b] = r[0];
}

// ---------------------------------------------------------------------------
// scan stage 2: exclusive scan of block sums (single block, nb <= 512)
// ---------------------------------------------------------------------------
__global__ __launch_bounds__(512) void scan2_kernel(uint* __restrict__ bsum, int nb) {
  __shared__ uint s[512];
  int t = threadIdx.x;
  uint v = (t < nb) ? bsum[t] : 0u;
  s[t] = v;
  __syncthreads();
  for (int d = 1; d < 512; d <<= 1) {
    uint add = (t >= d) ? s[t - d] : 0u;
    __syncthreads();
    s[t] += add;
    __syncthreads();
  }
  if (t < nb) bsum[t] = s[t] - v;   // exclusive
}

// ---------------------------------------------------------------------------
// scan stage 3: write seg offsets + idg = 1/max(cnt,1); last elem writes off[ns]
// ---------------------------------------------------------------------------
__global__ __launch_bounds__(256) void scan3_kernel(const uint* __restrict__ hist,
                                                    const uint* __restrict__ bsum,
                                                    uint* __restrict__ off,
                                                    float* __restrict__ idg,
                                                    int ns, int E) {
  __shared__ uint ts[256];
  int b = blockIdx.x, t = threadIdx.x;
  int base = b * 2048 + t * 8;
  uint h[8]; uint sum = 0;
#pragma unroll
  for (int i = 0; i < 8; ++i) { int k = base + i; h[i] = (k < ns) ? hist[k] : 0u; sum += h[i]; }
  ts[t] = sum;
  __syncthreads();
  uint own = sum;
  for (int d = 1; d < 256; d <<= 1) {
    uint add = (t >= d) ? ts[t - d] : 0u;
    __syncthreads();
    ts[t] += add;
    __syncthreads();
  }
  uint run = bsum[b] + (ts[t] - own);
#pragma unroll
  for (int i = 0; i < 8; ++i) {
    int k = base + i;
    if (k < ns) {
      off[k] = run;
      idg[k] = 1.0f / fmaxf((float)h[i], 1.0f);
      run += h[i];
      if (k == ns - 1) off[ns] = (uint)E;
    }
  }
}

// ---------------------------------------------------------------------------
// placement (atomic-free): sp[off[s] + rank[e]] = src*8 + rel
// 8 edges/thread, batched loads, 8 independent chains
// ---------------------------------------------------------------------------
__global__ __launch_bounds__(256) void place_kernel(const int* __restrict__ src,
                                                    const int* __restrict__ dst,
                                                    const int* __restrict__ et,
                                                    const uint* __restrict__ off,
                                                    const uint* __restrict__ rank,
                                                    uint* __restrict__ sp, int E) {
  int base = (blockIdx.x * 256 + threadIdx.x) * 8;
  if (base + 8 <= E) {
    int4 d0 = *(const int4*)&dst[base], d1 = *(const int4*)&dst[base + 4];
    int4 r0 = *(const int4*)&et[base],  r1 = *(const int4*)&et[base + 4];
    int4 s0 = *(const int4*)&src[base], s1 = *(const int4*)&src[base + 4];
    uint4 k0 = *(const uint4*)&rank[base], k1 = *(const uint4*)&rank[base + 4];
    int dd[8] = {d0.x, d0.y, d0.z, d0.w, d1.x, d1.y, d1.z, d1.w};
    int rr[8] = {r0.x, r0.y, r0.z, r0.w, r1.x, r1.y, r1.z, r1.w};
    int ss[8] = {s0.x, s0.y, s0.z, s0.w, s1.x, s1.y, s1.z, s1.w};
    uint kk[8] = {k0.x, k0.y, k0.z, k0.w, k1.x, k1.y, k1.z, k1.w};
    uint oo[8];
#pragma unroll
    for (int j = 0; j < 8; ++j) oo[j] = off[(size_t)dd[j] * NREL + rr[j]];
#pragma unroll
    for (int j = 0; j < 8; ++j)
      sp[oo[j] + kk[j]] = ((uint)ss[j] << 3) | (uint)rr[j];
  } else {
    for (int j = 0; base + j < E; ++j) {
      int e = base + j;
      int r = et[e];
      sp[off[(size_t)dst[e] * NREL + r] + rank[e]] = ((uint)src[e] << 3) | (uint)r;
    }
  }
}

// ---------------------------------------------------------------------------
// transpose-convert weights: out_bf16[r][n][k] = in_f32[r][k][n]
// ---------------------------------------------------------------------------
__global__ __launch_bounds__(256) void cvt_wt_kernel(const float* __restrict__ in,
                                                     ushort* __restrict__ out,
                                                     int R, int K, int N) {
  int idx = blockIdx.x * 256 + threadIdx.x;
  if (idx >= R * K * N) return;
  int r = idx / (K * N);
  int rem = idx - r * K * N;
  int n = rem / K;
  int k = rem - n * K;
  out[idx] = f2bf(in[(size_t)r * K * N + (size_t)k * N + n]);
}

// ---------------------------------------------------------------------------
// xt[m][r*64+n] = bf16( sum_k x[m][k] * W1[r][k][n] )   MFMA, swapped operands
// ---------------------------------------------------------------------------
__global__ __launch_bounds__(256) void gemm_xt_kernel(const float* __restrict__ x,
                                                      const ushort* __restrict__ W1t,
                                                      ushort* __restrict__ xt, int M) {
  __shared__ __align__(16) ushort Axs[64][136];
  __shared__ __align__(16) ushort Bws[64][136];
  const int tid = threadIdx.x;
  const int w = tid >> 6, l = tid & 63;
  const int rows0 = blockIdx.x * 64;
#pragma unroll
  for (int i = 0; i < 8; ++i) {
    int g = tid + 256 * i;
    int row = g >> 5, c4 = (g & 31) * 4;
    int rr = rows0 + row; if (rr >= M) rr = M - 1;
    float4 v = *(const float4*)&x[(size_t)rr * 128 + c4];
    *(ushort4*)&Axs[row][c4] = make_ushort4(f2bf(v.x), f2bf(v.y), f2bf(v.z), f2bf(v.w));
  }
  __syncthreads();
  const int mrow = w * 16 + (l & 15);
  const int koff = (l >> 4) * 8;
  bfrag8 xf[4];
#pragma unroll
  for (int kc = 0; kc < 4; ++kc)
    xf[kc] = *(const bfrag8*)&Axs[mrow][kc * 32 + koff];
  const int m = rows0 + mrow;
  for (int r = 0; r < NREL; ++r) {
    __syncthreads();
#pragma unroll
    for (int i = 0; i < 8; ++i) {
      int g = tid + 256 * i;
      int row = g >> 5, c4 = (g & 31) * 4;
      *(ushort4*)&Bws[row][c4] = *(const ushort4*)&W1t[((size_t)r * 64 + row) * 128 + c4];
    }
    __syncthreads();
#pragma unroll
    for (int ct = 0; ct < 4; ++ct) {
      facc4 acc = {0.f, 0.f, 0.f, 0.f};
#pragma unroll
      for (int kc = 0; kc < 4; ++kc) {
        bfrag8 af = *(const bfrag8*)&Bws[ct * 16 + (l & 15)][kc * 32 + koff];
        acc = __builtin_amdgcn_mfma_f32_16x16x32_bf16(af, xf[kc], acc, 0, 0, 0);
      }
      if (m < M) {
        int n0 = ct * 16 + (l >> 4) * 4;
        *(ushort4*)&xt[(size_t)m * 512 + r * 64 + n0] =
            make_ushort4(f2bf(acc[0]), f2bf(acc[1]), f2bf(acc[2]), f2bf(acc[3]));
      }
    }
  }
}

// ---------------------------------------------------------------------------
// agg1[d][lane] = sum_r idg[d,r] * sum_{e in seg(d,r)} xt[src_e][r][lane]
// one wave per dst; sp batch-loaded via lanes + shfl; gathers pipelined x8
// ---------------------------------------------------------------------------
__global__ __launch_bounds__(256) void agg1_kernel(const uint* __restrict__ off,
                                                   const uint* __restrict__ sp,
                                                   const float* __restrict__ idg,
                                                   const ushort* __restrict__ xt,
                                                   float* __restrict__ agg, int N, int E) {
  int wid = (blockIdx.x * 256 + threadIdx.x) >> 6;
  if (wid >= N) return;
  int lane = threadIdx.x & 63;
  uint e0 = off[(size_t)wid * 8], e1 = off[(size_t)wid * 8 + 8];
  float idgl = (lane < 8) ? idg[(size_t)wid * 8 + lane] : 0.f;
  float acc = 0.f;
  for (uint b0 = e0; b0 < e1; b0 += 64) {
    uint vsp = (b0 + (uint)lane < (uint)E) ? sp[b0 + lane] : 0u;
    int n = min(64, (int)(e1 - b0));
    int i = 0;
    for (; i + 8 <= n; i += 8) {
      uint p[8]; float v[8];
#pragma unroll
      for (int j = 0; j < 8; ++j) p[j] = __shfl(vsp, i + j);
#pragma unroll
      for (int j = 0; j < 8; ++j)
        v[j] = bf2f(xt[(size_t)(p[j] >> 3) * 512 + (p[j] & 7u) * 64 + lane]);
#pragma unroll
      for (int j = 0; j < 8; ++j)
        acc += v[j] * __shfl(idgl, (int)(p[j] & 7u));
    }
    for (; i < n; ++i) {
      uint pp = __shfl(vsp, i);
      acc += bf2f(xt[(size_t)(pp >> 3) * 512 + (pp & 7u) * 64 + lane]) *
             __shfl(idgl, (int)(pp & 7u));
    }
  }
  agg[(size_t)wid * 64 + lane] = acc;
}

// ---------------------------------------------------------------------------
// y2[d][r][lane] = bf16( idg[d,r] * sum_{e in seg(d,r)} h[src_e][lane] )
// flat edge loop, pipelined gathers x8, wave-uniform flush on rel change
// ---------------------------------------------------------------------------
__global__ __launch_bounds__(256) void agg2_kernel(const uint* __restrict__ off,
                                                   const uint* __restrict__ sp,
                                                   const float* __restrict__ idg,
                                                   const ushort* __restrict__ hb,
                                                   ushort* __restrict__ y2, int N, int E) {
  int wid = (blockIdx.x * 256 + threadIdx.x) >> 6;
  if (wid >= N) return;
  int lane = threadIdx.x & 63;
  uint e0 = off[(size_t)wid * 8], e1 = off[(size_t)wid * 8 + 8];
  float idgl = (lane < 8) ? idg[(size_t)wid * 8 + lane] : 0.f;
  float acc = 0.f;
  int curR = -1;
  uint written = 0;
  for (uint b0 = e0; b0 < e1; b0 += 64) {
    uint vsp = (b0 + (uint)lane < (uint)E) ? sp[b0 + lane] : 0u;
    int n = min(64, (int)(e1 - b0));
    int i = 0;
    for (; i + 8 <= n; i += 8) {
      uint p[8]; float v[8];
#pragma unroll
      for (int j = 0; j < 8; ++j) p[j] = __shfl(vsp, i + j);
#pragma unroll
      for (int j = 0; j < 8; ++j)
        v[j] = bf2f(hb[(size_t)(p[j] >> 3) * 64 + lane]);
#pragma unroll
      for (int j = 0; j < 8; ++j) {
        int r = (int)(p[j] & 7u);
        if (r != curR) {                 // wave-uniform (p from shfl)
          if (curR >= 0) {
            y2[(size_t)wid * 512 + curR * 64 + lane] = f2bf(acc * __shfl(idgl, curR));
            written |= 1u << curR;
          }
          acc = 0.f; curR = r;
        }
        acc += v[j];
      }
    }
    for (; i < n; ++i) {
      uint pp = __shfl(vsp, i);
      int r = (int)(pp & 7u);
      if (r != curR) {
        if (curR >= 0) {
          y2[(size_t)wid * 512 + curR * 64 + lane] = f2bf(acc * __shfl(idgl, curR));
          written |= 1u << curR;
        }
        acc = 0.f; curR = r;
      }
      acc += bf2f(hb[(size_t)(pp >> 3) * 64 + lane]);
    }
  }
  if (curR >= 0) {
    y2[(size_t)wid * 512 + curR * 64 + lane] = f2bf(acc * __shfl(idgl, curR));
    written |= 1u << curR;
  }
#pragma unroll
  for (int r = 0; r < 8; ++r)
    if (!((written >> r) & 1u))
      y2[(size_t)wid * 512 + r * 64 + lane] = 0;
}

// ---------------------------------------------------------------------------
// hb[m][n] = bf16( relu( agg[m][n] + (x root1)[m][n] + b1[n] ) )
// ---------------------------------------------------------------------------
__global__ __launch_bounds__(256) void reduce_h_kernel(const float* __restrict__ x,
                                                       const ushort* __restrict__ r1t,
                                                       const float* __restrict__ b1,
                                                       const float* __restrict__ agg,
                                                       ushort* __restrict__ hb, int M) {
  __shared__ __align__(16) ushort Axs[64][136];
  __shared__ __align__(16) ushort Bws[64][136];
  const int tid = threadIdx.x;
  const int w = tid >> 6, l = tid & 63;
  const int rows0 = blockIdx.x * 64;
#pragma unroll
  for (int i = 0; i < 8; ++i) {
    int g = tid + 256 * i;
    int row = g >> 5, c4 = (g & 31) * 4;
    int rr = rows0 + row; if (rr >= M) rr = M - 1;
    float4 v = *(const float4*)&x[(size_t)rr * 128 + c4];
    *(ushort4*)&Axs[row][c4] = make_ushort4(f2bf(v.x), f2bf(v.y), f2bf(v.z), f2bf(v.w));
    *(ushort4*)&Bws[row][c4] = *(const ushort4*)&r1t[(size_t)row * 128 + c4];
  }
  __syncthreads();
  const int mrow = w * 16 + (l & 15);
  const int koff = (l >> 4) * 8;
  const int m = rows0 + mrow;
  const int mc = (m < M) ? m : (M - 1);
  bfrag8 xf[4];
#pragma unroll
  for (int kc = 0; kc < 4; ++kc)
    xf[kc] = *(const bfrag8*)&Axs[mrow][kc * 32 + koff];
  facc4 acc[4] = {};
#pragma unroll
  for (int ct = 0; ct < 4; ++ct)
#pragma unroll
    for (int kc = 0; kc < 4; ++kc) {
      bfrag8 af = *(const bfrag8*)&Bws[ct * 16 + (l & 15)][kc * 32 + koff];
      acc[ct] = __builtin_amdgcn_mfma_f32_16x16x32_bf16(af, xf[kc], acc[ct], 0, 0, 0);
    }
#pragma unroll
  for (int ct = 0; ct < 4; ++ct) {
    int n0 = ct * 16 + (l >> 4) * 4;
    float4 s4 = *(const float4*)&agg[(size_t)mc * 64 + n0];
    float4 bb = *(const float4*)&b1[n0];
    float h0 = fmaxf(acc[ct][0] + s4.x + bb.x, 0.f);
    float h1 = fmaxf(acc[ct][1] + s4.y + bb.y, 0.f);
    float h2 = fmaxf(acc[ct][2] + s4.z + bb.z, 0.f);
    float h3 = fmaxf(acc[ct][3] + s4.w + bb.w, 0.f);
    if (m < M)
      *(ushort4*)&hb[(size_t)m * 64 + n0] =
          make_ushort4(f2bf(h0), f2bf(h1), f2bf(h2), f2bf(h3));
  }
}

// ---------------------------------------------------------------------------
// out[m][n] = sum_r y2[m][r][:] W2[r][:][n] + (h root2)[m][n] + b2[n]
// (y2 pre-normalized)
// ---------------------------------------------------------------------------
__global__ __launch_bounds__(256) void gemm_out_kernel(const ushort* __restrict__ hb,
                                                       const ushort* __restrict__ y2,
                                                       const ushort* __restrict__ W2t,
                                                       const ushort* __restrict__ r2t,
                                                       const float* __restrict__ b2,
                                                       float* __restrict__ out, int M) {
  __shared__ __align__(16) ushort Bws[128][72];
  const int tid = threadIdx.x;
  const int w = tid >> 6, l = tid & 63;
  const int rows0 = blockIdx.x * 64;
  const int mrow = w * 16 + (l & 15);
  const int koff = (l >> 4) * 8;
  const int m = rows0 + mrow;
  const int mc = (m < M) ? m : (M - 1);
  facc4 oacc[8] = {};
  // ---- root2 part ----
#pragma unroll
  for (int i = 0; i < 8; ++i) {
    int g = tid + 256 * i;
    int row = g >> 4, c4 = (g & 15) * 4;
    *(ushort4*)&Bws[row][c4] = *(const ushort4*)&r2t[(size_t)row * 64 + c4];
  }
  __syncthreads();
  {
    bfrag8 h0 = *(const bfrag8*)&hb[(size_t)mc * 64 + koff];
    bfrag8 h1 = *(const bfrag8*)&hb[(size_t)mc * 64 + 32 + koff];
#pragma unroll
    for (int ct = 0; ct < 8; ++ct) {
      bfrag8 a0 = *(const bfrag8*)&Bws[ct * 16 + (l & 15)][koff];
      bfrag8 a1 = *(const bfrag8*)&Bws[ct * 16 + (l & 15)][32 + koff];
      oacc[ct] = __builtin_amdgcn_mfma_f32_16x16x32_bf16(a0, h0, oacc[ct], 0, 0, 0);
      oacc[ct] = __builtin_amdgcn_mfma_f32_16x16x32_bf16(a1, h1, oacc[ct], 0, 0, 0);
    }
  }
  // ---- relation parts (y2 already normalized) ----
  for (int r = 0; r < NREL; ++r) {
    __syncthreads();
#pragma unroll
    for (int i = 0; i < 8; ++i) {
      int g = tid + 256 * i;
      int row = g >> 4, c4 = (g & 15) * 4;
      *(ushort4*)&Bws[row][c4] = *(const ushort4*)&W2t[((size_t)r * 128 + row) * 64 + c4];
    }
    __syncthreads();
    bfrag8 y0 = *(const bfrag8*)&y2[(size_t)mc * 512 + r * 64 + koff];
    bfrag8 y1f = *(const bfrag8*)&y2[(size_t)mc * 512 + r * 64 + 32 + koff];
#pragma unroll
    for (int ct = 0; ct < 8; ++ct) {
      bfrag8 a0 = *(const bfrag8*)&Bws[ct * 16 + (l & 15)][koff];
      bfrag8 a1 = *(const bfrag8*)&Bws[ct * 16 + (l & 15)][32 + koff];
      oacc[ct] = __builtin_amdgcn_mfma_f32_16x16x32_bf16(a0, y0, oacc[ct], 0, 0, 0);
      oacc[ct] = __builtin_amdgcn_mfma_f32_16x16x32_bf16(a1, y1f, oacc[ct], 0, 0, 0);
    }
  }
  if (m < M) {
#pragma unroll
    for (int ct = 0; ct < 8; ++ct) {
      int n0 = ct * 16 + (l >> 4) * 4;
      float4 bb = *(const float4*)&b2[n0];
      float4 o = make_float4(oacc[ct][0] + bb.x, oacc[ct][1] + bb.y,
                             oacc[ct][2] + bb.z, oacc[ct][3] + bb.w);
      *(float4*)&out[(size_t)m * 128 + n0] = o;
    }
  }
}

// ---------------------------------------------------------------------------
extern "C" void kernel_launch(void* const* d_in, const int* in_sizes, int n_in,
                              void* d_out, int out_size, void* d_ws, size_t ws_size,
                              hipStream_t stream) {
  const float* x     = (const float*)d_in[0];
  const int*   ei    = (const int*)d_in[1];
  const int*   et    = (const int*)d_in[2];
  const float* W1    = (const float*)d_in[3];
  const float* root1 = (const float*)d_in[4];
  const float* b1    = (const float*)d_in[5];
  const float* W2    = (const float*)d_in[6];
  const float* root2 = (const float*)d_in[7];
  const float* b2    = (const float*)d_in[8];
  float* out = (float*)d_out;

  const int M = in_sizes[0] / 128;   // 100000
  const int E = in_sizes[2];         // 1600000
  const int NS = M * NREL;           // segments
  const int* srcp = ei;
  const int* dstp = ei + E;

  auto align = [](char*& p, size_t n) { char* q = p; p += (n + 255) & ~(size_t)255; return q; };
  char* p = (char*)d_ws;
  ushort* xt   = (ushort*)align(p, (size_t)M * 512 * 2);  // layer1 xt / layer2 y2 (alias)
  float*  agg  = (float*) align(p, (size_t)M * 64 * 4);
  ushort* hb   = (ushort*)align(p, (size_t)M * 64 * 2);
  uint*   hist = (uint*)  align(p, (size_t)NS * 4);
  uint*   rank = (uint*)  align(p, (size_t)E * 4);
  uint*   off  = (uint*)  align(p, (size_t)(NS + 1) * 4);
  float*  idg  = (float*) align(p, (size_t)NS * 4);
  uint*   sp   = (uint*)  align(p, (size_t)E * 4);
  uint*   bsum = (uint*)  align(p, 4096);
  ushort* W1t  = (ushort*)align(p, (size_t)NREL * 64 * 128 * 2);
  ushort* r1t  = (ushort*)align(p, (size_t)64 * 128 * 2);
  ushort* W2t  = (ushort*)align(p, (size_t)NREL * 128 * 64 * 2);
  ushort* r2t  = (ushort*)align(p, (size_t)128 * 64 * 2);
  ushort* y2 = xt;

  // tiny weight transpose-converts
  cvt_wt_kernel<<<(NREL * 128 * 64 + 255) / 256, 256, 0, stream>>>(W1, W1t, NREL, 128, 64);
  cvt_wt_kernel<<<(128 * 64 + 255) / 256, 256, 0, stream>>>(root1, r1t, 1, 128, 64);
  cvt_wt_kernel<<<(NREL * 64 * 128 + 255) / 256, 256, 0, stream>>>(W2, W2t, NREL, 64, 128);
  cvt_wt_kernel<<<(64 * 128 + 255) / 256, 256, 0, stream>>>(root2, r2t, 1, 64, 128);

  // ---- counting sort by (dst, rel): hist(+rank) -> scan -> place ----
  hipMemsetAsync(hist, 0, (size_t)NS * 4, stream);
  const int E8B = (int)(((long long)E + 8LL * 256 - 1) / (8LL * 256));
  hist_kernel<<<E8B, 256, 0, stream>>>(dstp, et, hist, rank, E);
  const int NB = (NS + 2047) / 2048;
  scan1_kernel<<<NB, 256, 0, stream>>>(hist, bsum, NS);
  scan2_kernel<<<1, 512, 0, stream>>>(bsum, NB);
  scan3_kernel<<<NB, 256, 0, stream>>>(hist, bsum, off, idg, NS, E);
  place_kernel<<<E8B, 256, 0, stream>>>(srcp, dstp, et, off, rank, sp, E);

  const int MB64 = (M + 63) / 64;
  const int AGB = (M * 64 + 255) / 256;   // one wave per dst

  // ---- layer 1: transform -> sorted gather-aggregate -> root+relu ----
  gemm_xt_kernel<<<MB64, 256, 0, stream>>>(x, W1t, xt, M);
  agg1_kernel<<<AGB, 256, 0, stream>>>(off, sp, idg, xt, agg, M, E);
  reduce_h_kernel<<<MB64, 256, 0, stream>>>(x, r1t, b1, agg, hb, M);

  // ---- layer 2: sorted gather-aggregate (pre-normalized) -> fused GEMM ----
  agg2_kernel<<<AGB, 256, 0, stream>>>(off, sp, idg, hb, y2, M, E);
  gemm_out_kernel<<<MB64, 256, 0, stream>>>(hb, y2, W2t, r2t, b2, out, M);
}